// Round 2
// baseline (3829.677 us; speedup 1.0000x reference)
//
#include <hip/hip_runtime.h>
#include <math.h>

#define B_ 16
#define A_ 32
#define G_ 512
#define S_ 4096
#define M_ 8
#define BS_ 65536
#define FE_ 100

// ---------------- helpers ----------------
__device__ __forceinline__ float wave_sum_f(float v){
#pragma unroll
  for (int o = 32; o > 0; o >>= 1) v += __shfl_xor(v, o);
  return v;
}
__device__ __forceinline__ float wave_max_f(float v){
#pragma unroll
  for (int o = 32; o > 0; o >>= 1) v = fmaxf(v, __shfl_xor(v, o));
  return v;
}
__device__ __forceinline__ float sigmoidf_(float x){ return 1.f/(1.f+__expf(-x)); }
__device__ __forceinline__ float tanhf_(float x){ return 1.f - 2.f/(__expf(2.f*x)+1.f); }

// ---------------- K0: prefix-sum W_ih rows within each 20-wide field --------
__global__ __launch_bounds__(256) void k_prefix(const float* __restrict__ W_ih,
                                                float* __restrict__ Pw){
  int j = blockIdx.x*256 + threadIdx.x;
  if (j >= 1536) return;
  const float* src = W_ih + (size_t)j*FE_;
  float* dst = Pw + (size_t)j*FE_;
#pragma unroll
  for (int f = 0; f < 5; ++f){
    int off = f*20;
    float run = 0.f;
#pragma unroll
    for (int k = 0; k < 20; ++k){ run += src[off+k]; dst[off+k] = run; }
  }
}

// ---------------- K1: prep — swvs einsum, LN, counts ------------------------
// 1D grid: rows/16 blocks; block handles 16 consecutive rows (same batch since
// row_base is 16-aligned and 16 | 4096). normed is chunk-local, cpk global.
__global__ __launch_bounds__(256) void k_prep(
    const float* __restrict__ vf, const float* __restrict__ mask,
    const float* __restrict__ eoh, const float* __restrict__ subs,
    const float* __restrict__ ln_g, const float* __restrict__ ln_b,
    float* __restrict__ normed, int* __restrict__ cpk, int row0){
  __shared__ float s_m[A_];
  __shared__ float s_e[A_*5];
  __shared__ float s_sub[A_];
  __shared__ float s_sm[A_];
  __shared__ float s_red[8];
  __shared__ int   s_cnt[5];
  int row_base = row0 + blockIdx.x*16;      // global row of first subset
  int b  = row_base >> 12;                  // 4096 rows per batch
  int s_base = row_base & (S_-1);
  int tid = threadIdx.x;
  if (tid < A_)   s_m[tid] = mask[b*A_ + tid];
  if (tid < A_*5) s_e[tid] = eoh[b*A_*5 + tid];
  __syncthreads();
  int g0 = tid*2;
  float2 vfm[A_];
#pragma unroll
  for (int a = 0; a < A_; ++a){
    float2 v = *(const float2*)(vf + ((size_t)b*A_ + a)*G_ + g0);
    float mk = s_m[a];
    vfm[a] = make_float2(v.x*mk, v.y*mk);
  }
  float2 lw = *(const float2*)(ln_g + g0);
  float2 lb = *(const float2*)(ln_b + g0);
  int lane = tid & 63, wv = tid >> 6;
  for (int si = 0; si < 16; ++si){
    int s = s_base + si;
    if (tid < A_){
      float v = subs[((size_t)b*S_ + s)*A_ + tid];
      s_sub[tid] = v;
      s_sm[tid]  = v * s_m[tid];
    }
    __syncthreads();
    float ssum = 0.f; float swx = 0.f, swy = 0.f;
#pragma unroll
    for (int a = 0; a < A_; ++a){
      float sm = s_sm[a];
      ssum += sm;
      swx += vfm[a].x * sm;
      swy += vfm[a].y * sm;
    }
    float inv = 1.f/(ssum + 1e-4f);
    float mx = swx*inv, my = swy*inv;
    float r1 = mx + my, r2 = mx*mx + my*my;
    r1 = wave_sum_f(r1); r2 = wave_sum_f(r2);
    if (lane == 0){ s_red[wv] = r1; s_red[4+wv] = r2; }
    __syncthreads();
    if (tid == 0){
      s_red[0] = s_red[0]+s_red[1]+s_red[2]+s_red[3];
      s_red[4] = s_red[4]+s_red[5]+s_red[6]+s_red[7];
    }
    if (tid >= 8 && tid < 13){
      int e = tid - 8;
      float c = 0.f;
#pragma unroll
      for (int a = 0; a < A_; ++a) c += s_e[a*5+e]*s_sub[a];
      int ci = (int)(c + 0.5f);
      ci = min(max(ci, 0), 19);
      s_cnt[e] = ci;
    }
    __syncthreads();
    float mu  = s_red[0] * (1.f/512.f);
    float var = s_red[4] * (1.f/512.f) - mu*mu;
    float rs  = rsqrtf(var + 1e-5f);
    float2 o;
    o.x = (mx-mu)*rs*lw.x + lb.x;
    o.y = (my-mu)*rs*lw.y + lb.y;
    size_t lrow = (size_t)blockIdx.x*16 + si;          // chunk-local row
    *(float2*)(normed + lrow*G_ + g0) = o;
    if (tid == 0)
      cpk[row_base + si] = s_cnt[0] | (s_cnt[1]<<6) | (s_cnt[2]<<12) | (s_cnt[3]<<18) | (s_cnt[4]<<24);
    __syncthreads();
  }
}

// ---------------- K2: GRU (gh GEMM ×3 gates + gi lookup + elementwise) ------
// grid (rows/64, 512/64), block 256. 64x64 tile, 4x4 per thread, 3 gates.
// Aact/Hout chunk-local; cpk indexed globally via row0.
__global__ __launch_bounds__(256) void k_gru(
    const float* __restrict__ Aact, const float* __restrict__ Whh,
    const float* __restrict__ bih, const float* __restrict__ bhh,
    const float* __restrict__ Pw, const int* __restrict__ cpk,
    float* __restrict__ Hout, int row0){
  __shared__ float sA[16][68];
  __shared__ float sW[3][16][68];
  int tid = threadIdx.x;
  int bm = blockIdx.x, bn = blockIdx.y;
  int tx = tid & 15, ty = tid >> 4;
  int m0 = bm*64, n0 = bn*64;               // m0 chunk-local
  float acc[3][4][4] = {};
  int lr = tid >> 2;
  int k4 = (tid & 3) * 4;
  const float* Aptr = Aact + (size_t)(m0 + lr)*G_ + k4;
  for (int kc = 0; kc < G_; kc += 16){
    float4 a4 = *(const float4*)(Aptr + kc);
    sA[k4+0][lr] = a4.x; sA[k4+1][lr] = a4.y; sA[k4+2][lr] = a4.z; sA[k4+3][lr] = a4.w;
#pragma unroll
    for (int g = 0; g < 3; ++g){
      float4 w4 = *(const float4*)(Whh + (size_t)(g*512 + n0 + lr)*G_ + kc + k4);
      sW[g][k4+0][lr] = w4.x; sW[g][k4+1][lr] = w4.y; sW[g][k4+2][lr] = w4.z; sW[g][k4+3][lr] = w4.w;
    }
    __syncthreads();
#pragma unroll
    for (int k = 0; k < 16; ++k){
      float av[4];
      *(float4*)av = *(const float4*)&sA[k][ty*4];
      float wvv[3][4];
#pragma unroll
      for (int g = 0; g < 3; ++g) *(float4*)wvv[g] = *(const float4*)&sW[g][k][tx*4];
#pragma unroll
      for (int g = 0; g < 3; ++g)
#pragma unroll
        for (int r = 0; r < 4; ++r)
#pragma unroll
          for (int c = 0; c < 4; ++c)
            acc[g][r][c] += av[r]*wvv[g][c];
    }
    __syncthreads();
  }
  // epilogue: gi lookups + GRU math
#pragma unroll
  for (int r = 0; r < 4; ++r){
    int lm = m0 + ty*4 + r;                 // chunk-local row
    int cp = cpk[row0 + lm];                // global row
    int i0 =  (cp      ) & 63;
    int i1 = ((cp >> 6 ) & 63) + 20;
    int i2 = ((cp >> 12) & 63) + 40;
    int i3 = ((cp >> 18) & 63) + 60;
    int i4 = ((cp >> 24) & 63) + 80;
    float hv[4];
#pragma unroll
    for (int c = 0; c < 4; ++c){
      int d = n0 + tx*4 + c;
      float gr = acc[0][r][c] + bhh[d];
      float gz = acc[1][r][c] + bhh[512+d];
      float gn = acc[2][r][c] + bhh[1024+d];
      const float* P0 = Pw + (size_t)d*FE_;
      const float* P1 = Pw + (size_t)(512+d)*FE_;
      const float* P2 = Pw + (size_t)(1024+d)*FE_;
      float ir = bih[d]      + P0[i0]+P0[i1]+P0[i2]+P0[i3]+P0[i4];
      float iz = bih[512+d]  + P1[i0]+P1[i1]+P1[i2]+P1[i3]+P1[i4];
      float in_= bih[1024+d] + P2[i0]+P2[i1]+P2[i2]+P2[i3]+P2[i4];
      float rr = sigmoidf_(ir + gr);
      float zz = sigmoidf_(iz + gz);
      float nn = tanhf_(in_ + rr*gn);
      float hp = Aact[(size_t)lm*G_ + d];
      hv[c] = (1.f-zz)*nn + zz*hp;
    }
    *(float4*)(Hout + (size_t)lm*G_ + n0 + tx*4) = *(float4*)hv;
  }
}

// ---------------- K3: FF layer relu(A @ W^T + b), chunk-local ---------------
__global__ __launch_bounds__(256) void k_ff(
    const float* __restrict__ Ain, const float* __restrict__ W,
    const float* __restrict__ bias, float* __restrict__ Out){
  __shared__ float sA[16][68];
  __shared__ float sW[16][68];
  int tid = threadIdx.x;
  int bm = blockIdx.x, bn = blockIdx.y;
  int tx = tid & 15, ty = tid >> 4;
  int m0 = bm*64, n0 = bn*64;
  float acc[4][4] = {};
  int lr = tid >> 2;
  int k4 = (tid & 3) * 4;
  const float* Aptr = Ain + (size_t)(m0 + lr)*G_ + k4;
  const float* Wptr = W + (size_t)(n0 + lr)*G_ + k4;
  for (int kc = 0; kc < G_; kc += 16){
    float4 a4 = *(const float4*)(Aptr + kc);
    sA[k4+0][lr] = a4.x; sA[k4+1][lr] = a4.y; sA[k4+2][lr] = a4.z; sA[k4+3][lr] = a4.w;
    float4 w4 = *(const float4*)(Wptr + kc);
    sW[k4+0][lr] = w4.x; sW[k4+1][lr] = w4.y; sW[k4+2][lr] = w4.z; sW[k4+3][lr] = w4.w;
    __syncthreads();
#pragma unroll
    for (int k = 0; k < 16; ++k){
      float av[4], wv[4];
      *(float4*)av = *(const float4*)&sA[k][ty*4];
      *(float4*)wv = *(const float4*)&sW[k][tx*4];
#pragma unroll
      for (int r = 0; r < 4; ++r)
#pragma unroll
        for (int c = 0; c < 4; ++c)
          acc[r][c] += av[r]*wv[c];
    }
    __syncthreads();
  }
#pragma unroll
  for (int r = 0; r < 4; ++r){
    int lm = m0 + ty*4 + r;
    float v[4];
#pragma unroll
    for (int c = 0; c < 4; ++c){
      float o = acc[r][c] + bias[n0 + tx*4 + c];
      v[c] = fmaxf(o, 0.f);
    }
    *(float4*)(Out + (size_t)lm*G_ + n0 + tx*4) = *(float4*)v;
  }
}

// ---------------- K4: final LN + score (X chunk-local, scores global) -------
__global__ __launch_bounds__(256) void k_ln_score(
    const float* __restrict__ X, const float* __restrict__ g,
    const float* __restrict__ bta, const float* __restrict__ Ws,
    const float* __restrict__ bs, float* __restrict__ scores, int row0){
  int tid = threadIdx.x, lane = tid & 63, wv = tid >> 6;
  size_t lrow0 = (size_t)blockIdx.x*32 + wv*8;
  int e0 = lane*8;
  float4 w0 = *(const float4*)(Ws + e0);
  float4 w1 = *(const float4*)(Ws + e0 + 4);
  float4 g0v = *(const float4*)(g + e0);
  float4 g1v = *(const float4*)(g + e0 + 4);
  float4 b0v = *(const float4*)(bta + e0);
  float4 b1v = *(const float4*)(bta + e0 + 4);
  float bsv = bs[0];
  for (int rr = 0; rr < 8; ++rr){
    size_t lrow = lrow0 + rr;
    const float* xp = X + lrow*G_ + e0;
    float4 v0 = *(const float4*)xp;
    float4 v1 = *(const float4*)(xp+4);
    float s1 = v0.x+v0.y+v0.z+v0.w + v1.x+v1.y+v1.z+v1.w;
    float s2 = v0.x*v0.x+v0.y*v0.y+v0.z*v0.z+v0.w*v0.w
             + v1.x*v1.x+v1.y*v1.y+v1.z*v1.z+v1.w*v1.w;
    s1 = wave_sum_f(s1); s2 = wave_sum_f(s2);
    float mu = s1*(1.f/512.f);
    float var = s2*(1.f/512.f) - mu*mu;
    float rs = rsqrtf(var + 1e-5f);
    float sc =
      ((v0.x-mu)*rs*g0v.x + b0v.x)*w0.x + ((v0.y-mu)*rs*g0v.y + b0v.y)*w0.y +
      ((v0.z-mu)*rs*g0v.z + b0v.z)*w0.z + ((v0.w-mu)*rs*g0v.w + b0v.w)*w0.w +
      ((v1.x-mu)*rs*g1v.x + b1v.x)*w1.x + ((v1.y-mu)*rs*g1v.y + b1v.y)*w1.y +
      ((v1.z-mu)*rs*g1v.z + b1v.z)*w1.z + ((v1.w-mu)*rs*g1v.w + b1v.w)*w1.w;
    sc = wave_sum_f(sc);
    if (lane == 0) scores[row0 + lrow] = sc + bsv;
  }
}

// ---------------- K5: softmax over S per batch ------------------------------
__global__ __launch_bounds__(256) void k_softmax(
    const float* __restrict__ scores, float* __restrict__ probs){
  __shared__ float red[4];
  int b = blockIdx.x, tid = threadIdx.x, lane = tid & 63, wv = tid >> 6;
  const float* sp = scores + (size_t)b*S_;
  float mx = -1e30f;
  for (int i = tid; i < S_; i += 256) mx = fmaxf(mx, sp[i]);
  mx = wave_max_f(mx);
  if (lane == 0) red[wv] = mx;
  __syncthreads();
  mx = fmaxf(fmaxf(red[0], red[1]), fmaxf(red[2], red[3]));
  __syncthreads();
  float sum = 0.f;
  for (int i = tid; i < S_; i += 256) sum += __expf(sp[i]-mx);
  sum = wave_sum_f(sum);
  if (lane == 0) red[wv] = sum;
  __syncthreads();
  sum = red[0]+red[1]+red[2]+red[3];
  float inv = 1.f/sum;
  for (int i = tid; i < S_; i += 256)
    probs[(size_t)b*S_ + i] = __expf(sp[i]-mx)*inv;
}

// ---------------- K6: spectrum scatter --------------------------------------
__global__ __launch_bounds__(256) void k_spect(
    const float* __restrict__ peaks, const float* __restrict__ probs,
    float* __restrict__ spect){
  __shared__ float bins[512];
  int b = blockIdx.x, tid = threadIdx.x;
  bins[tid] = 0.f; bins[tid+256] = 0.f;
  __syncthreads();
  for (int i = tid; i < S_*M_; i += 256){
    int s = i >> 3, m = i & 7;
    const float* pk = peaks + (((size_t)b*S_ + s)*M_ + m)*2;
    float mass = pk[0], inten = pk[1];
    float p = probs[(size_t)b*S_ + s];
    int bin = (int)rintf(mass);
    bin = min(max(bin, 0), 511);
    atomicAdd(&bins[bin], inten*p);
  }
  __syncthreads();
  spect[(size_t)b*512 + tid]       = bins[tid];
  spect[(size_t)b*512 + tid + 256] = bins[tid+256];
}

// ---------------- launcher --------------------------------------------------
extern "C" void kernel_launch(void* const* d_in, const int* in_sizes, int n_in,
                              void* d_out, int out_size, void* d_ws, size_t ws_size,
                              hipStream_t stream) {
  const float* vf       = (const float*)d_in[0];
  const float* mask     = (const float*)d_in[1];
  const float* eoh      = (const float*)d_in[2];
  const float* subs     = (const float*)d_in[4];
  const float* peaks    = (const float*)d_in[5];
  const float* ln_sub_g = (const float*)d_in[6];
  const float* ln_sub_b = (const float*)d_in[7];
  const float* W_ih     = (const float*)d_in[8];
  const float* W_hh     = (const float*)d_in[9];
  const float* b_ih     = (const float*)d_in[10];
  const float* b_hh     = (const float*)d_in[11];
  const float* W1       = (const float*)d_in[12];
  const float* b1       = (const float*)d_in[13];
  const float* W2a      = (const float*)d_in[14];
  const float* b2a      = (const float*)d_in[15];
  const float* W2b      = (const float*)d_in[16];
  const float* b2b      = (const float*)d_in[17];
  const float* ln_pre_g = (const float*)d_in[18];
  const float* ln_pre_b = (const float*)d_in[19];
  const float* Ws       = (const float*)d_in[20];
  const float* bs       = (const float*)d_in[21];
  float* out = (float*)d_out;            // [0,8192) spect, [8192,73728) probs
  float* probs_out = out + (size_t)B_*512;

  // Fixed small allocations, then size the per-chunk ping-pong buffers from
  // ws_size (constant across calls -> identical launch sequence every call).
  char* w = (char*)d_ws;
  float* Pw = (float*)w;      w += (size_t)1536*FE_*4;   // 614,400 B
  int*   cpk = (int*)w;       w += (size_t)BS_*4;        // 262,144 B
  float* scores = (float*)w;  w += (size_t)BS_*4;        // 262,144 B
  w = (char*)(((uintptr_t)w + 255) & ~(uintptr_t)255);
  size_t used  = (size_t)(w - (char*)d_ws);
  size_t avail = (ws_size > used) ? (ws_size - used) : 0;
  long long fit = (long long)(avail / (2ull * G_ * sizeof(float)));  // rows for 2 buffers
  int CR = (int)((fit / 64) * 64);
  if (CR > BS_) CR = BS_;
  if (CR < 64)  CR = 64;   // below this nothing fits; assume ws >= ~4 MB
  float* buf0 = (float*)w;
  float* buf1 = buf0 + (size_t)CR * G_;

  k_prefix<<<6, 256, 0, stream>>>(W_ih, Pw);
  for (int r0 = 0; r0 < BS_; r0 += CR){
    int rows = (BS_ - r0 < CR) ? (BS_ - r0) : CR;   // multiple of 64
    k_prep<<<rows/16, 256, 0, stream>>>(vf, mask, eoh, subs,
                                        ln_sub_g, ln_sub_b, buf0, cpk, r0);
    k_gru<<<dim3(rows/64, 8), 256, 0, stream>>>(buf0, W_hh, b_ih, b_hh, Pw, cpk, buf1, r0);
    k_ff<<<dim3(rows/64, 8), 256, 0, stream>>>(buf1, W1,  b1,  buf0);   // x1
    k_ff<<<dim3(rows/64, 8), 256, 0, stream>>>(buf0, W2a, b2a, buf1);   // x2
    k_ff<<<dim3(rows/64, 8), 256, 0, stream>>>(buf1, W2b, b2b, buf0);   // x3
    k_ln_score<<<rows/32, 256, 0, stream>>>(buf0, ln_pre_g, ln_pre_b, Ws, bs, scores, r0);
  }
  k_softmax<<<B_, 256, 0, stream>>>(scores, probs_out);
  k_spect<<<B_, 256, 0, stream>>>(peaks, probs_out, out);
}

// Round 3
// 1191.204 us; speedup vs baseline: 3.2150x; 3.2150x over previous
//
#include <hip/hip_runtime.h>
#include <math.h>

#define B_ 16
#define A_ 32
#define G_ 512
#define S_ 4096
#define M_ 8
#define BS_ 65536
#define FE_ 100

typedef _Float16 half8 __attribute__((ext_vector_type(8)));
typedef _Float16 half4v __attribute__((ext_vector_type(4)));
typedef _Float16 half2v __attribute__((ext_vector_type(2)));
typedef float floatx4 __attribute__((ext_vector_type(4)));

typedef const __attribute__((address_space(1))) void* gas_t;
typedef __attribute__((address_space(3))) void* las_t;

// ---------------- helpers ----------------
__device__ __forceinline__ float wave_sum_f(float v){
#pragma unroll
  for (int o = 32; o > 0; o >>= 1) v += __shfl_xor(v, o);
  return v;
}
__device__ __forceinline__ float wave_max_f(float v){
#pragma unroll
  for (int o = 32; o > 0; o >>= 1) v = fmaxf(v, __shfl_xor(v, o));
  return v;
}
__device__ __forceinline__ float sigmoidf_(float x){ return 1.f/(1.f+__expf(-x)); }
__device__ __forceinline__ float tanhf_(float x){ return 1.f - 2.f/(__expf(2.f*x)+1.f); }

// ---------------- K0a: fp32 -> fp16 convert (n % 4 == 0) --------------------
__global__ __launch_bounds__(256) void k_cvt(const float* __restrict__ s,
                                             _Float16* __restrict__ d, int n){
  int i = (blockIdx.x*256 + threadIdx.x)*4;
  if (i >= n) return;
  float4 v = *(const float4*)(s+i);
  half4v o; o[0]=(_Float16)v.x; o[1]=(_Float16)v.y; o[2]=(_Float16)v.z; o[3]=(_Float16)v.w;
  *(half4v*)(d+i) = o;
}

// ---------------- K0b: prefix-sum W_ih rows within each 20-wide field -------
__global__ __launch_bounds__(256) void k_prefix(const float* __restrict__ W_ih,
                                                float* __restrict__ Pw){
  int j = blockIdx.x*256 + threadIdx.x;
  if (j >= 1536) return;
  const float* src = W_ih + (size_t)j*FE_;
  float* dst = Pw + (size_t)j*FE_;
#pragma unroll
  for (int f = 0; f < 5; ++f){
    int off = f*20;
    float run = 0.f;
#pragma unroll
    for (int k = 0; k < 20; ++k){ run += src[off+k]; dst[off+k] = run; }
  }
}

// ---------------- K1: prep — swvs einsum, LN, counts; fp16 normed out ------
__global__ __launch_bounds__(256) void k_prep(
    const float* __restrict__ vf, const float* __restrict__ mask,
    const float* __restrict__ eoh, const float* __restrict__ subs,
    const float* __restrict__ ln_g, const float* __restrict__ ln_b,
    _Float16* __restrict__ normed, int* __restrict__ cpk){
  __shared__ float s_m[A_];
  __shared__ float s_e[A_*5];
  __shared__ float s_sub[A_];
  __shared__ float s_sm[A_];
  __shared__ float s_red[8];
  __shared__ int   s_cnt[5];
  int row_base = blockIdx.x*16;
  int b  = row_base >> 12;
  int s_base = row_base & (S_-1);
  int tid = threadIdx.x;
  if (tid < A_)   s_m[tid] = mask[b*A_ + tid];
  if (tid < A_*5) s_e[tid] = eoh[b*A_*5 + tid];
  __syncthreads();
  int g0 = tid*2;
  float2 vfm[A_];
#pragma unroll
  for (int a = 0; a < A_; ++a){
    float2 v = *(const float2*)(vf + ((size_t)b*A_ + a)*G_ + g0);
    float mk = s_m[a];
    vfm[a] = make_float2(v.x*mk, v.y*mk);
  }
  float2 lw = *(const float2*)(ln_g + g0);
  float2 lb = *(const float2*)(ln_b + g0);
  int lane = tid & 63, wv = tid >> 6;
  for (int si = 0; si < 16; ++si){
    int s = s_base + si;
    if (tid < A_){
      float v = subs[((size_t)b*S_ + s)*A_ + tid];
      s_sub[tid] = v;
      s_sm[tid]  = v * s_m[tid];
    }
    __syncthreads();
    float ssum = 0.f; float swx = 0.f, swy = 0.f;
#pragma unroll
    for (int a = 0; a < A_; ++a){
      float sm = s_sm[a];
      ssum += sm;
      swx += vfm[a].x * sm;
      swy += vfm[a].y * sm;
    }
    float inv = 1.f/(ssum + 1e-4f);
    float mx = swx*inv, my = swy*inv;
    float r1 = mx + my, r2 = mx*mx + my*my;
    r1 = wave_sum_f(r1); r2 = wave_sum_f(r2);
    if (lane == 0){ s_red[wv] = r1; s_red[4+wv] = r2; }
    __syncthreads();
    if (tid == 0){
      s_red[0] = s_red[0]+s_red[1]+s_red[2]+s_red[3];
      s_red[4] = s_red[4]+s_red[5]+s_red[6]+s_red[7];
    }
    if (tid >= 8 && tid < 13){
      int e = tid - 8;
      float c = 0.f;
#pragma unroll
      for (int a = 0; a < A_; ++a) c += s_e[a*5+e]*s_sub[a];
      int ci = (int)(c + 0.5f);
      ci = min(max(ci, 0), 19);
      s_cnt[e] = ci;
    }
    __syncthreads();
    float mu  = s_red[0] * (1.f/512.f);
    float var = s_red[4] * (1.f/512.f) - mu*mu;
    float rs  = rsqrtf(var + 1e-5f);
    half2v o16;
    o16[0] = (_Float16)((mx-mu)*rs*lw.x + lb.x);
    o16[1] = (_Float16)((my-mu)*rs*lw.y + lb.y);
    size_t row = (size_t)row_base + si;
    *(half2v*)(normed + row*G_ + g0) = o16;
    if (tid == 0)
      cpk[row] = s_cnt[0] | (s_cnt[1]<<6) | (s_cnt[2]<<12) | (s_cnt[3]<<18) | (s_cnt[4]<<24);
    __syncthreads();
  }
}

// ---------------- K2: GRU — fp16 MFMA, 3 gates fused ------------------------
// grid (512, 8): block tile M=128, N=64 dims (3 gates). BK=32, 16 K-chunks.
// Waves 2x2: wave tile 64 (m) x 32 (n-dims) x 3 gates.
__global__ __launch_bounds__(256) void k_gru16(
    const _Float16* __restrict__ Aact, const _Float16* __restrict__ W3,
    const float* __restrict__ bih, const float* __restrict__ bhh,
    const float* __restrict__ Pw, const int* __restrict__ cpk,
    _Float16* __restrict__ Hout){
  __shared__ _Float16 smA[128*32];   // 8 KB
  __shared__ _Float16 smB[192*32];   // 12 KB
  int tid = threadIdx.x;
  int lane = tid & 63, wvid = tid >> 6;
  int wm = wvid & 1, wn = wvid >> 1;
  int q = lane >> 4, l15 = lane & 15;
  int m0 = blockIdx.x*128, n0 = blockIdx.y*64;
  floatx4 acc[3][4][2] = {};
  // frag LDS element offsets (XOR-swizzled 16B units)
  int offA[4], offB[3][2];
#pragma unroll
  for (int i = 0; i < 4; ++i){
    int r = wm*64 + i*16 + l15;
    offA[i] = (r*4 + (q ^ (r&3)))*8;
  }
#pragma unroll
  for (int g = 0; g < 3; ++g)
#pragma unroll
    for (int j = 0; j < 2; ++j){
      int rb = g*64 + wn*32 + j*16 + l15;
      offB[g][j] = (rb*4 + (q ^ (rb&3)))*8;
    }
  for (int kc = 0; kc < G_; kc += 32){
    // stage A: 512 units in 8 segs; wave handles 2
#pragma unroll
    for (int t = 0; t < 2; ++t){
      int seg = wvid*2 + t;
      int u = seg*64 + lane;
      int r = u >> 2, c = (u & 3) ^ (r & 3);
      const _Float16* ga = Aact + (size_t)(m0 + r)*G_ + kc + c*8;
      __builtin_amdgcn_global_load_lds((gas_t)ga, (las_t)(smA + seg*512), 16, 0, 0);
    }
    // stage B: 768 units in 12 segs; wave handles 3
#pragma unroll
    for (int t = 0; t < 3; ++t){
      int seg = wvid*3 + t;
      int u = seg*64 + lane;
      int rb = u >> 2, c = (u & 3) ^ (rb & 3);
      int grow = (rb >> 6)*512 + n0 + (rb & 63);
      const _Float16* gb = W3 + (size_t)grow*G_ + kc + c*8;
      __builtin_amdgcn_global_load_lds((gas_t)gb, (las_t)(smB + seg*512), 16, 0, 0);
    }
    __syncthreads();
    half8 af[4], bf[3][2];
#pragma unroll
    for (int i = 0; i < 4; ++i) af[i] = *(const half8*)(smA + offA[i]);
#pragma unroll
    for (int g = 0; g < 3; ++g)
#pragma unroll
      for (int j = 0; j < 2; ++j) bf[g][j] = *(const half8*)(smB + offB[g][j]);
#pragma unroll
    for (int g = 0; g < 3; ++g)
#pragma unroll
      for (int i = 0; i < 4; ++i)
#pragma unroll
        for (int j = 0; j < 2; ++j)
          acc[g][i][j] = __builtin_amdgcn_mfma_f32_16x16x32_f16(af[i], bf[g][j], acc[g][i][j], 0, 0, 0);
    __syncthreads();
  }
  // epilogue: gi lookups + GRU math
  int   dj[2];
  float bhr[2], bhz[2], bhn[2], bir[2], biz[2], bin_[2];
#pragma unroll
  for (int j = 0; j < 2; ++j){
    int d = n0 + wn*32 + j*16 + l15;
    dj[j] = d;
    bhr[j] = bhh[d]; bhz[j] = bhh[512+d]; bhn[j] = bhh[1024+d];
    bir[j] = bih[d]; biz[j] = bih[512+d]; bin_[j] = bih[1024+d];
  }
#pragma unroll
  for (int i = 0; i < 4; ++i){
#pragma unroll
    for (int r = 0; r < 4; ++r){
      int m = m0 + wm*64 + i*16 + q*4 + r;
      int cp = cpk[m];
      int i0 =  (cp      ) & 63;
      int i1 = ((cp >> 6 ) & 63) + 20;
      int i2 = ((cp >> 12) & 63) + 40;
      int i3 = ((cp >> 18) & 63) + 60;
      int i4 = ((cp >> 24) & 63) + 80;
#pragma unroll
      for (int j = 0; j < 2; ++j){
        int d = dj[j];
        const float* P0 = Pw + (size_t)d*FE_;
        const float* P1 = Pw + (size_t)(512+d)*FE_;
        const float* P2 = Pw + (size_t)(1024+d)*FE_;
        float ir = bir[j]  + P0[i0]+P0[i1]+P0[i2]+P0[i3]+P0[i4];
        float iz = biz[j]  + P1[i0]+P1[i1]+P1[i2]+P1[i3]+P1[i4];
        float in_= bin_[j] + P2[i0]+P2[i1]+P2[i2]+P2[i3]+P2[i4];
        float gr = acc[0][i][j][r] + bhr[j];
        float gz = acc[1][i][j][r] + bhz[j];
        float gn = acc[2][i][j][r] + bhn[j];
        float rr = sigmoidf_(ir + gr);
        float zz = sigmoidf_(iz + gz);
        float nn = tanhf_(in_ + rr*gn);
        float hp = (float)Aact[(size_t)m*G_ + d];
        Hout[(size_t)m*G_ + d] = (_Float16)((1.f-zz)*nn + zz*hp);
      }
    }
  }
}

// ---------------- K3: FF relu(A @ W^T + b) — fp16 MFMA ----------------------
// grid (512, 4): block tile 128x128, waves 2x2, wave tile 64x64. BK=32.
__global__ __launch_bounds__(256) void k_ff16(
    const _Float16* __restrict__ A, const _Float16* __restrict__ W,
    const float* __restrict__ bias, _Float16* __restrict__ Out){
  __shared__ _Float16 smA[128*32];
  __shared__ _Float16 smB[128*32];
  int tid = threadIdx.x;
  int lane = tid & 63, wvid = tid >> 6;
  int wm = wvid & 1, wn = wvid >> 1;
  int q = lane >> 4, l15 = lane & 15;
  int m0 = blockIdx.x*128, n0 = blockIdx.y*128;
  floatx4 acc[4][4] = {};
  int offA[4], offB[4];
#pragma unroll
  for (int i = 0; i < 4; ++i){
    int r = wm*64 + i*16 + l15;
    offA[i] = (r*4 + (q ^ (r&3)))*8;
    int n = wn*64 + i*16 + l15;
    offB[i] = (n*4 + (q ^ (n&3)))*8;
  }
  for (int kc = 0; kc < G_; kc += 32){
#pragma unroll
    for (int t = 0; t < 2; ++t){
      int seg = wvid*2 + t;
      int u = seg*64 + lane;
      int r = u >> 2, c = (u & 3) ^ (r & 3);
      const _Float16* ga = A + (size_t)(m0 + r)*G_ + kc + c*8;
      __builtin_amdgcn_global_load_lds((gas_t)ga, (las_t)(smA + seg*512), 16, 0, 0);
      const _Float16* gb = W + (size_t)(n0 + r)*G_ + kc + c*8;
      __builtin_amdgcn_global_load_lds((gas_t)gb, (las_t)(smB + seg*512), 16, 0, 0);
    }
    __syncthreads();
    half8 af[4], bf[4];
#pragma unroll
    for (int i = 0; i < 4; ++i) af[i] = *(const half8*)(smA + offA[i]);
#pragma unroll
    for (int j = 0; j < 4; ++j) bf[j] = *(const half8*)(smB + offB[j]);
#pragma unroll
    for (int i = 0; i < 4; ++i)
#pragma unroll
      for (int j = 0; j < 4; ++j)
        acc[i][j] = __builtin_amdgcn_mfma_f32_16x16x32_f16(af[i], bf[j], acc[i][j], 0, 0, 0);
    __syncthreads();
  }
#pragma unroll
  for (int j = 0; j < 4; ++j){
    int n = n0 + wn*64 + j*16 + l15;
    float bv = bias[n];
#pragma unroll
    for (int i = 0; i < 4; ++i){
#pragma unroll
      for (int r = 0; r < 4; ++r){
        int m = m0 + wm*64 + i*16 + q*4 + r;
        Out[(size_t)m*G_ + n] = (_Float16)fmaxf(acc[i][j][r] + bv, 0.f);
      }
    }
  }
}

// ---------------- K4: final LN + score (fp16 in, fp32 out) ------------------
__global__ __launch_bounds__(256) void k_ln_score(
    const _Float16* __restrict__ X, const float* __restrict__ g,
    const float* __restrict__ bta, const float* __restrict__ Ws,
    const float* __restrict__ bs, float* __restrict__ scores){
  int tid = threadIdx.x, lane = tid & 63, wv = tid >> 6;
  size_t row0 = (size_t)blockIdx.x*32 + wv*8;
  int e0 = lane*8;
  float wv_[8], gv[8], bv[8];
  *(float4*)(wv_ ) = *(const float4*)(Ws + e0);
  *(float4*)(wv_+4) = *(const float4*)(Ws + e0 + 4);
  *(float4*)(gv  ) = *(const float4*)(g + e0);
  *(float4*)(gv+4) = *(const float4*)(g + e0 + 4);
  *(float4*)(bv  ) = *(const float4*)(bta + e0);
  *(float4*)(bv+4) = *(const float4*)(bta + e0 + 4);
  float bsv = bs[0];
  for (int rr = 0; rr < 8; ++rr){
    size_t row = row0 + rr;
    half8 hx = *(const half8*)(X + row*G_ + e0);
    float xv[8];
#pragma unroll
    for (int t = 0; t < 8; ++t) xv[t] = (float)hx[t];
    float s1 = 0.f, s2 = 0.f;
#pragma unroll
    for (int t = 0; t < 8; ++t){ s1 += xv[t]; s2 += xv[t]*xv[t]; }
    s1 = wave_sum_f(s1); s2 = wave_sum_f(s2);
    float mu = s1*(1.f/512.f);
    float var = s2*(1.f/512.f) - mu*mu;
    float rs = rsqrtf(var + 1e-5f);
    float sc = 0.f;
#pragma unroll
    for (int t = 0; t < 8; ++t) sc += ((xv[t]-mu)*rs*gv[t] + bv[t])*wv_[t];
    sc = wave_sum_f(sc);
    if (lane == 0) scores[row] = sc + bsv;
  }
}

// ---------------- K5: softmax over S per batch ------------------------------
__global__ __launch_bounds__(256) void k_softmax(
    const float* __restrict__ scores, float* __restrict__ probs){
  __shared__ float red[4];
  int b = blockIdx.x, tid = threadIdx.x, lane = tid & 63, wv = tid >> 6;
  const float* sp = scores + (size_t)b*S_;
  float mx = -1e30f;
  for (int i = tid; i < S_; i += 256) mx = fmaxf(mx, sp[i]);
  mx = wave_max_f(mx);
  if (lane == 0) red[wv] = mx;
  __syncthreads();
  mx = fmaxf(fmaxf(red[0], red[1]), fmaxf(red[2], red[3]));
  __syncthreads();
  float sum = 0.f;
  for (int i = tid; i < S_; i += 256) sum += __expf(sp[i]-mx);
  sum = wave_sum_f(sum);
  if (lane == 0) red[wv] = sum;
  __syncthreads();
  sum = red[0]+red[1]+red[2]+red[3];
  float inv = 1.f/sum;
  for (int i = tid; i < S_; i += 256)
    probs[(size_t)b*S_ + i] = __expf(sp[i]-mx)*inv;
}

// ---------------- K6: spectrum scatter --------------------------------------
__global__ __launch_bounds__(256) void k_spect(
    const float* __restrict__ peaks, const float* __restrict__ probs,
    float* __restrict__ spect){
  __shared__ float bins[512];
  int b = blockIdx.x, tid = threadIdx.x;
  bins[tid] = 0.f; bins[tid+256] = 0.f;
  __syncthreads();
  for (int i = tid; i < S_*M_; i += 256){
    int s = i >> 3, m = i & 7;
    const float* pk = peaks + (((size_t)b*S_ + s)*M_ + m)*2;
    float mass = pk[0], inten = pk[1];
    float p = probs[(size_t)b*S_ + s];
    int bin = (int)rintf(mass);
    bin = min(max(bin, 0), 511);
    atomicAdd(&bins[bin], inten*p);
  }
  __syncthreads();
  spect[(size_t)b*512 + tid]       = bins[tid];
  spect[(size_t)b*512 + tid + 256] = bins[tid+256];
}

// ---------------- launcher --------------------------------------------------
extern "C" void kernel_launch(void* const* d_in, const int* in_sizes, int n_in,
                              void* d_out, int out_size, void* d_ws, size_t ws_size,
                              hipStream_t stream) {
  const float* vf       = (const float*)d_in[0];
  const float* mask     = (const float*)d_in[1];
  const float* eoh      = (const float*)d_in[2];
  const float* subs     = (const float*)d_in[4];
  const float* peaks    = (const float*)d_in[5];
  const float* ln_sub_g = (const float*)d_in[6];
  const float* ln_sub_b = (const float*)d_in[7];
  const float* W_ih     = (const float*)d_in[8];
  const float* W_hh     = (const float*)d_in[9];
  const float* b_ih     = (const float*)d_in[10];
  const float* b_hh     = (const float*)d_in[11];
  const float* W1       = (const float*)d_in[12];
  const float* b1       = (const float*)d_in[13];
  const float* W2a      = (const float*)d_in[14];
  const float* b2a      = (const float*)d_in[15];
  const float* W2b      = (const float*)d_in[16];
  const float* b2b      = (const float*)d_in[17];
  const float* ln_pre_g = (const float*)d_in[18];
  const float* ln_pre_b = (const float*)d_in[19];
  const float* Ws       = (const float*)d_in[20];
  const float* bs       = (const float*)d_in[21];
  float* out = (float*)d_out;            // [0,8192) spect, [8192,73728) probs
  float* probs_out = out + (size_t)B_*512;

  // workspace carve (~206 MB total; round-2 run proved ws >= 270 MB)
  char* w = (char*)d_ws;
  float* Pw = (float*)w;         w += (size_t)1536*FE_*4;      // 614400
  int*   cpk = (int*)w;          w += (size_t)BS_*4;           // 262144
  float* scores = (float*)w;     w += (size_t)BS_*4;           // 262144
  _Float16* W3h  = (_Float16*)w; w += (size_t)1536*G_*2;       // 1.5 MB
  _Float16* W1h  = (_Float16*)w; w += (size_t)G_*G_*2;
  _Float16* W2ah = (_Float16*)w; w += (size_t)G_*G_*2;
  _Float16* W2bh = (_Float16*)w; w += (size_t)G_*G_*2;
  _Float16* normedh = (_Float16*)w; w += (size_t)BS_*G_*2;     // 67 MB
  _Float16* bufh0   = (_Float16*)w; w += (size_t)BS_*G_*2;     // 67 MB
  _Float16* bufh1   = (_Float16*)w;                            // 67 MB

  k_cvt<<<(1536*G_/4+255)/256, 256, 0, stream>>>(W_hh, W3h, 1536*G_);
  k_cvt<<<(G_*G_/4+255)/256,   256, 0, stream>>>(W1,  W1h,  G_*G_);
  k_cvt<<<(G_*G_/4+255)/256,   256, 0, stream>>>(W2a, W2ah, G_*G_);
  k_cvt<<<(G_*G_/4+255)/256,   256, 0, stream>>>(W2b, W2bh, G_*G_);
  k_prefix<<<6, 256, 0, stream>>>(W_ih, Pw);
  k_prep<<<BS_/16, 256, 0, stream>>>(vf, mask, eoh, subs,
                                     ln_sub_g, ln_sub_b, normedh, cpk);
  k_gru16<<<dim3(BS_/128, 8), 256, 0, stream>>>(normedh, W3h, b_ih, b_hh, Pw, cpk, bufh0);
  k_ff16<<<dim3(BS_/128, 4), 256, 0, stream>>>(bufh0, W1h,  b1,  bufh1);  // x1
  k_ff16<<<dim3(BS_/128, 4), 256, 0, stream>>>(bufh1, W2ah, b2a, bufh0);  // x2
  k_ff16<<<dim3(BS_/128, 4), 256, 0, stream>>>(bufh0, W2bh, b2b, bufh1);  // x3
  k_ln_score<<<BS_/32, 256, 0, stream>>>(bufh1, ln_pre_g, ln_pre_b, Ws, bs, scores);
  k_softmax<<<B_, 256, 0, stream>>>(scores, probs_out);
  k_spect<<<B_, 256, 0, stream>>>(peaks, probs_out, out);
}

// Round 4
// 818.788 us; speedup vs baseline: 4.6773x; 1.4548x over previous
//
#include <hip/hip_runtime.h>
#include <math.h>

#define B_ 16
#define A_ 32
#define G_ 512
#define S_ 4096
#define M_ 8
#define BS_ 65536
#define KC_ 640      // concat K: 512 normed + 100 OH + 28 pad
#define NG_ 1536
#define CH_ 8192     // gh chunk rows

typedef _Float16 half8 __attribute__((ext_vector_type(8)));
typedef _Float16 half4v __attribute__((ext_vector_type(4)));
typedef _Float16 half2v __attribute__((ext_vector_type(2)));
typedef float floatx4 __attribute__((ext_vector_type(4)));

typedef const __attribute__((address_space(1))) void* gas_t;
typedef __attribute__((address_space(3))) void* las_t;

// ---------------- helpers ----------------
__device__ __forceinline__ float wave_sum_f(float v){
#pragma unroll
  for (int o = 32; o > 0; o >>= 1) v += __shfl_xor(v, o);
  return v;
}
__device__ __forceinline__ float wave_max_f(float v){
#pragma unroll
  for (int o = 32; o > 0; o >>= 1) v = fmaxf(v, __shfl_xor(v, o));
  return v;
}
__device__ __forceinline__ float sigmoidf_(float x){ return 1.f/(1.f+__expf(-x)); }
__device__ __forceinline__ float tanhf_(float x){ return 1.f - 2.f/(__expf(2.f*x)+1.f); }

// ---------------- K0a: fp32 -> fp16 convert (n % 4 == 0) --------------------
__global__ __launch_bounds__(256) void k_cvt(const float* __restrict__ s,
                                             _Float16* __restrict__ d, int n){
  int i = (blockIdx.x*256 + threadIdx.x)*4;
  if (i >= n) return;
  float4 v = *(const float4*)(s+i);
  half4v o; o[0]=(_Float16)v.x; o[1]=(_Float16)v.y; o[2]=(_Float16)v.z; o[3]=(_Float16)v.w;
  *(half4v*)(d+i) = o;
}

// ---------------- K0b: build Wcat[1536][640] = [W_hh | W_ih(r,z) | 0] -------
__global__ __launch_bounds__(64) void k_buildw(const float* __restrict__ Whh,
                                               const float* __restrict__ Wih,
                                               _Float16* __restrict__ Wcat){
  int j = blockIdx.x;
  for (int p = threadIdx.x; p < KC_; p += 64){
    float v = 0.f;
    if (p < 512) v = Whh[(size_t)j*512 + p];
    else if (p < 612 && j < 1024) v = Wih[(size_t)j*100 + (p - 512)];
    Wcat[(size_t)j*KC_ + p] = (_Float16)v;
  }
}

// ---------------- K0c: Pn[100][512] — transposed prefix table for i_n -------
__global__ __launch_bounds__(256) void k_pn(const float* __restrict__ Wih,
                                            float* __restrict__ Pn){
  int d = blockIdx.x*256 + threadIdx.x;
  if (d >= 512) return;
  const float* src = Wih + (size_t)(1024 + d)*100;
#pragma unroll
  for (int f = 0; f < 5; ++f){
    int off = f*20;
    float run = 0.f;
    for (int k = 0; k < 20; ++k){
      run += src[off + k];
      Pn[(size_t)(off + k)*512 + d] = run;
    }
  }
}

// ---------------- K1: prep — swvs einsum, LN, counts, OH; fp16 A out --------
// Writes A rows of width KC_=640: [0,512)=normed fp16, [512,640)=thermometer/pad
__global__ __launch_bounds__(256) void k_prep(
    const float* __restrict__ vf, const float* __restrict__ mask,
    const float* __restrict__ eoh, const float* __restrict__ subs,
    const float* __restrict__ ln_g, const float* __restrict__ ln_b,
    _Float16* __restrict__ Abuf, int* __restrict__ cpk){
  __shared__ float s_m[A_];
  __shared__ float s_e[A_*5];
  __shared__ float s_sub[A_];
  __shared__ float s_sm[A_];
  __shared__ float s_red[8];
  __shared__ int   s_cnt[5];
  int row_base = blockIdx.x*16;
  int b  = row_base >> 12;
  int s_base = row_base & (S_-1);
  int tid = threadIdx.x;
  if (tid < A_)   s_m[tid] = mask[b*A_ + tid];
  if (tid < A_*5) s_e[tid] = eoh[b*A_*5 + tid];
  __syncthreads();
  int g0 = tid*2;
  float2 vfm[A_];
#pragma unroll
  for (int a = 0; a < A_; ++a){
    float2 v = *(const float2*)(vf + ((size_t)b*A_ + a)*G_ + g0);
    float mk = s_m[a];
    vfm[a] = make_float2(v.x*mk, v.y*mk);
  }
  float2 lw = *(const float2*)(ln_g + g0);
  float2 lb = *(const float2*)(ln_b + g0);
  int lane = tid & 63, wv = tid >> 6;
  for (int si = 0; si < 16; ++si){
    int s = s_base + si;
    if (tid < A_){
      float v = subs[((size_t)b*S_ + s)*A_ + tid];
      s_sub[tid] = v;
      s_sm[tid]  = v * s_m[tid];
    }
    __syncthreads();
    float ssum = 0.f; float swx = 0.f, swy = 0.f;
#pragma unroll
    for (int a = 0; a < A_; ++a){
      float sm = s_sm[a];
      ssum += sm;
      swx += vfm[a].x * sm;
      swy += vfm[a].y * sm;
    }
    float inv = 1.f/(ssum + 1e-4f);
    float mx = swx*inv, my = swy*inv;
    float r1 = mx + my, r2 = mx*mx + my*my;
    r1 = wave_sum_f(r1); r2 = wave_sum_f(r2);
    if (lane == 0){ s_red[wv] = r1; s_red[4+wv] = r2; }
    __syncthreads();
    if (tid == 0){
      s_red[0] = s_red[0]+s_red[1]+s_red[2]+s_red[3];
      s_red[4] = s_red[4]+s_red[5]+s_red[6]+s_red[7];
    }
    if (tid >= 8 && tid < 13){
      int e = tid - 8;
      float c = 0.f;
#pragma unroll
      for (int a = 0; a < A_; ++a) c += s_e[a*5+e]*s_sub[a];
      int ci = (int)(c + 0.5f);
      ci = min(max(ci, 0), 19);
      s_cnt[e] = ci;
    }
    __syncthreads();
    float mu  = s_red[0] * (1.f/512.f);
    float var = s_red[4] * (1.f/512.f) - mu*mu;
    float rs  = rsqrtf(var + 1e-5f);
    size_t row = (size_t)row_base + si;
    half2v o16;
    o16[0] = (_Float16)((mx-mu)*rs*lw.x + lb.x);
    o16[1] = (_Float16)((my-mu)*rs*lw.y + lb.y);
    *(half2v*)(Abuf + row*KC_ + g0) = o16;
    if (tid < 64){
      // thermometer one-hot columns [512,640)
      half2v t;
#pragma unroll
      for (int u = 0; u < 2; ++u){
        int k = tid*2 + u;
        float v = 0.f;
        if (k < 100){
          int f = k/20, l = k - f*20;
          v = (l <= s_cnt[f]) ? 1.f : 0.f;
        }
        t[u] = (_Float16)v;
      }
      *(half2v*)(Abuf + row*KC_ + 512 + tid*2) = t;
    }
    if (tid == 0)
      cpk[row] = s_cnt[0] | (s_cnt[1]<<6) | (s_cnt[2]<<12) | (s_cnt[3]<<18) | (s_cnt[4]<<24);
    __syncthreads();
  }
}

// ---------------- K2: generic fp16 MFMA GEMM  Out = [relu](A @ W^T + bias) --
// A:[M][K] fp16, W:[N][K] fp16, Out:[M][N] fp16. grid (M/128, N/128).
// 128x128 tile, BK=32, waves 2x2 (wave tile 64x64). Swizzle q^((r>>2)&3):
// uniform 2-way bank aliasing (free on CDNA4).
__global__ __launch_bounds__(256) void k_gemm(
    const _Float16* __restrict__ A, const _Float16* __restrict__ W,
    const float* __restrict__ bias, _Float16* __restrict__ Out,
    int K, int N, int relu){
  __shared__ _Float16 smA[128*32];
  __shared__ _Float16 smB[128*32];
  int tid = threadIdx.x;
  int lane = tid & 63, wvid = tid >> 6;
  int wm = wvid & 1, wn = wvid >> 1;
  int q = lane >> 4, l15 = lane & 15;
  int m0 = blockIdx.x*128, n0 = blockIdx.y*128;
  floatx4 acc[4][4] = {};
  int offA[4], offB[4];
#pragma unroll
  for (int i = 0; i < 4; ++i){
    int r = wm*64 + i*16 + l15;
    offA[i] = (r*4 + (q ^ ((r>>2)&3)))*8;
    int rb = wn*64 + i*16 + l15;
    offB[i] = (rb*4 + (q ^ ((rb>>2)&3)))*8;
  }
  // staging: 512 16B-units per matrix, 8 segs of 64 lanes; wave does 2 of each
  int uA[2], uB[2];
  const _Float16 *gA[2], *gB[2];
#pragma unroll
  for (int t = 0; t < 2; ++t){
    int seg = wvid*2 + t;
    int u = seg*64 + lane;
    int r = u >> 2, c = (u & 3) ^ ((r >> 2) & 3);
    uA[t] = seg;
    gA[t] = A + (size_t)(m0 + r)*K + c*8;
    gB[t] = W + (size_t)(n0 + r)*K + c*8;
  }
  for (int kc = 0; kc < K; kc += 32){
#pragma unroll
    for (int t = 0; t < 2; ++t){
      __builtin_amdgcn_global_load_lds((gas_t)(gA[t] + kc), (las_t)(smA + uA[t]*512), 16, 0, 0);
      __builtin_amdgcn_global_load_lds((gas_t)(gB[t] + kc), (las_t)(smB + uA[t]*512), 16, 0, 0);
    }
    __syncthreads();
    half8 af[4], bf[4];
#pragma unroll
    for (int i = 0; i < 4; ++i) af[i] = *(const half8*)(smA + offA[i]);
#pragma unroll
    for (int j = 0; j < 4; ++j) bf[j] = *(const half8*)(smB + offB[j]);
#pragma unroll
    for (int i = 0; i < 4; ++i)
#pragma unroll
      for (int j = 0; j < 4; ++j)
        acc[i][j] = __builtin_amdgcn_mfma_f32_16x16x32_f16(af[i], bf[j], acc[i][j], 0, 0, 0);
    __syncthreads();
  }
#pragma unroll
  for (int j = 0; j < 4; ++j){
    int n = n0 + wn*64 + j*16 + l15;
    float bv = bias ? bias[n] : 0.f;
#pragma unroll
    for (int i = 0; i < 4; ++i){
#pragma unroll
      for (int r = 0; r < 4; ++r){
        int m = m0 + wm*64 + i*16 + q*4 + r;
        float o = acc[i][j][r] + bv;
        if (relu) o = fmaxf(o, 0.f);
        Out[(size_t)m*N + n] = (_Float16)o;
      }
    }
  }
}

// ---------------- K3: GRU elementwise -------------------------------------
// ghc: [CH][1536] (i+h summed for r,z; h only for n). Abuf for normed (highway).
__global__ __launch_bounds__(256) void k_gruelem(
    const _Float16* __restrict__ ghc, const _Float16* __restrict__ Abuf,
    const float* __restrict__ Pn, const float* __restrict__ bih,
    const float* __restrict__ bhh, const int* __restrict__ cpk,
    _Float16* __restrict__ H, int row0){
  int tid = threadIdx.x;
  int d = tid*2;
  float2 br_i = *(const float2*)(bih + d);
  float2 bz_i = *(const float2*)(bih + 512 + d);
  float2 bn_i = *(const float2*)(bih + 1024 + d);
  float2 br_h = *(const float2*)(bhh + d);
  float2 bz_h = *(const float2*)(bhh + 512 + d);
  float2 bn_h = *(const float2*)(bhh + 1024 + d);
  int lrow0 = blockIdx.x*4;
  for (int rr = 0; rr < 4; ++rr){
    int lrow = lrow0 + rr;
    int grow = row0 + lrow;
    int cp = cpk[grow];
    int k0 =  (cp      ) & 63;
    int k1 = ((cp >> 6 ) & 63) + 20;
    int k2 = ((cp >> 12) & 63) + 40;
    int k3 = ((cp >> 18) & 63) + 60;
    int k4 = ((cp >> 24) & 63) + 80;
    float2 p0 = *(const float2*)(Pn + (size_t)k0*512 + d);
    float2 p1 = *(const float2*)(Pn + (size_t)k1*512 + d);
    float2 p2 = *(const float2*)(Pn + (size_t)k2*512 + d);
    float2 p3 = *(const float2*)(Pn + (size_t)k3*512 + d);
    float2 p4 = *(const float2*)(Pn + (size_t)k4*512 + d);
    half2v ghr = *(const half2v*)(ghc + (size_t)lrow*NG_ + d);
    half2v ghz = *(const half2v*)(ghc + (size_t)lrow*NG_ + 512 + d);
    half2v ghn = *(const half2v*)(ghc + (size_t)lrow*NG_ + 1024 + d);
    half2v nrm = *(const half2v*)(Abuf + (size_t)grow*KC_ + d);
    half2v hv;
#pragma unroll
    for (int u = 0; u < 2; ++u){
      float gr = (float)ghr[u] + (u ? br_i.y + br_h.y : br_i.x + br_h.x);
      float gz = (float)ghz[u] + (u ? bz_i.y + bz_h.y : bz_i.x + bz_h.x);
      float hn = (float)ghn[u] + (u ? bn_h.y : bn_h.x);
      float in_ = (u ? bn_i.y + p0.y+p1.y+p2.y+p3.y+p4.y
                     : bn_i.x + p0.x+p1.x+p2.x+p3.x+p4.x);
      float r = sigmoidf_(gr);
      float z = sigmoidf_(gz);
      float n = tanhf_(in_ + r*hn);
      float hp = (float)nrm[u];
      hv[u] = (_Float16)((1.f-z)*n + z*hp);
    }
    *(half2v*)(H + (size_t)grow*G_ + d) = hv;
  }
}

// ---------------- K4: final LN + score (fp16 in, fp32 out) ------------------
__global__ __launch_bounds__(256) void k_ln_score(
    const _Float16* __restrict__ X, const float* __restrict__ g,
    const float* __restrict__ bta, const float* __restrict__ Ws,
    const float* __restrict__ bs, float* __restrict__ scores){
  int tid = threadIdx.x, lane = tid & 63, wv = tid >> 6;
  size_t row0 = (size_t)blockIdx.x*32 + wv*8;
  int e0 = lane*8;
  float wv_[8], gv[8], bv[8];
  *(float4*)(wv_ ) = *(const float4*)(Ws + e0);
  *(float4*)(wv_+4) = *(const float4*)(Ws + e0 + 4);
  *(float4*)(gv  ) = *(const float4*)(g + e0);
  *(float4*)(gv+4) = *(const float4*)(g + e0 + 4);
  *(float4*)(bv  ) = *(const float4*)(bta + e0);
  *(float4*)(bv+4) = *(const float4*)(bta + e0 + 4);
  float bsv = bs[0];
  for (int rr = 0; rr < 8; ++rr){
    size_t row = row0 + rr;
    half8 hx = *(const half8*)(X + row*G_ + e0);
    float xv[8];
#pragma unroll
    for (int t = 0; t < 8; ++t) xv[t] = (float)hx[t];
    float s1 = 0.f, s2 = 0.f;
#pragma unroll
    for (int t = 0; t < 8; ++t){ s1 += xv[t]; s2 += xv[t]*xv[t]; }
    s1 = wave_sum_f(s1); s2 = wave_sum_f(s2);
    float mu = s1*(1.f/512.f);
    float var = s2*(1.f/512.f) - mu*mu;
    float rs = rsqrtf(var + 1e-5f);
    float sc = 0.f;
#pragma unroll
    for (int t = 0; t < 8; ++t) sc += ((xv[t]-mu)*rs*gv[t] + bv[t])*wv_[t];
    sc = wave_sum_f(sc);
    if (lane == 0) scores[row] = sc + bsv;
  }
}

// ---------------- K5: softmax over S per batch ------------------------------
__global__ __launch_bounds__(256) void k_softmax(
    const float* __restrict__ scores, float* __restrict__ probs){
  __shared__ float red[4];
  int b = blockIdx.x, tid = threadIdx.x, lane = tid & 63, wv = tid >> 6;
  const float* sp = scores + (size_t)b*S_;
  float mx = -1e30f;
  for (int i = tid; i < S_; i += 256) mx = fmaxf(mx, sp[i]);
  mx = wave_max_f(mx);
  if (lane == 0) red[wv] = mx;
  __syncthreads();
  mx = fmaxf(fmaxf(red[0], red[1]), fmaxf(red[2], red[3]));
  __syncthreads();
  float sum = 0.f;
  for (int i = tid; i < S_; i += 256) sum += __expf(sp[i]-mx);
  sum = wave_sum_f(sum);
  if (lane == 0) red[wv] = sum;
  __syncthreads();
  sum = red[0]+red[1]+red[2]+red[3];
  float inv = 1.f/sum;
  for (int i = tid; i < S_; i += 256)
    probs[(size_t)b*S_ + i] = __expf(sp[i]-mx)*inv;
}

// ---------------- K6: spectrum scatter --------------------------------------
__global__ __launch_bounds__(256) void k_spect(
    const float* __restrict__ peaks, const float* __restrict__ probs,
    float* __restrict__ spect){
  __shared__ float bins[512];
  int b = blockIdx.x, tid = threadIdx.x;
  bins[tid] = 0.f; bins[tid+256] = 0.f;
  __syncthreads();
  for (int i = tid; i < S_*M_; i += 256){
    int s = i >> 3, m = i & 7;
    const float* pk = peaks + (((size_t)b*S_ + s)*M_ + m)*2;
    float mass = pk[0], inten = pk[1];
    float p = probs[(size_t)b*S_ + s];
    int bin = (int)rintf(mass);
    bin = min(max(bin, 0), 511);
    atomicAdd(&bins[bin], inten*p);
  }
  __syncthreads();
  spect[(size_t)b*512 + tid]       = bins[tid];
  spect[(size_t)b*512 + tid + 256] = bins[tid+256];
}

// ---------------- launcher --------------------------------------------------
extern "C" void kernel_launch(void* const* d_in, const int* in_sizes, int n_in,
                              void* d_out, int out_size, void* d_ws, size_t ws_size,
                              hipStream_t stream) {
  const float* vf       = (const float*)d_in[0];
  const float* mask     = (const float*)d_in[1];
  const float* eoh      = (const float*)d_in[2];
  const float* subs     = (const float*)d_in[4];
  const float* peaks    = (const float*)d_in[5];
  const float* ln_sub_g = (const float*)d_in[6];
  const float* ln_sub_b = (const float*)d_in[7];
  const float* W_ih     = (const float*)d_in[8];
  const float* W_hh     = (const float*)d_in[9];
  const float* b_ih     = (const float*)d_in[10];
  const float* b_hh     = (const float*)d_in[11];
  const float* W1       = (const float*)d_in[12];
  const float* b1       = (const float*)d_in[13];
  const float* W2a      = (const float*)d_in[14];
  const float* b2a      = (const float*)d_in[15];
  const float* W2b      = (const float*)d_in[16];
  const float* b2b      = (const float*)d_in[17];
  const float* ln_pre_g = (const float*)d_in[18];
  const float* ln_pre_b = (const float*)d_in[19];
  const float* Ws       = (const float*)d_in[20];
  const float* bs       = (const float*)d_in[21];
  float* out = (float*)d_out;            // [0,8192) spect, [8192,73728) probs
  float* probs_out = out + (size_t)B_*512;

  // workspace carve — total ~180 MB (round-3 proved ws >= ~205 MB)
  char* w = (char*)d_ws;
  float* Pn = (float*)w;         w += (size_t)100*512*4;       // 204800
  int*   cpk = (int*)w;          w += (size_t)BS_*4;           // 262144
  float* scores = (float*)w;     w += (size_t)BS_*4;           // 262144
  _Float16* Wcat = (_Float16*)w; w += (size_t)NG_*KC_*2;       // ~2 MB
  _Float16* W1h  = (_Float16*)w; w += (size_t)G_*G_*2;
  _Float16* W2ah = (_Float16*)w; w += (size_t)G_*G_*2;
  _Float16* W2bh = (_Float16*)w; w += (size_t)G_*G_*2;
  _Float16* Abuf = (_Float16*)w; w += (size_t)BS_*KC_*2;       // 84 MB
  _Float16* bufh0 = (_Float16*)w; w += (size_t)BS_*G_*2;       // 67 MB
  _Float16* ghc   = (_Float16*)w;                              // 25 MB (chunk)
  _Float16* bufh1 = Abuf;        // reuse A region after GRU phase (84 >= 67 MB)

  k_cvt<<<(G_*G_/4+255)/256, 256, 0, stream>>>(W1,  W1h,  G_*G_);
  k_cvt<<<(G_*G_/4+255)/256, 256, 0, stream>>>(W2a, W2ah, G_*G_);
  k_cvt<<<(G_*G_/4+255)/256, 256, 0, stream>>>(W2b, W2bh, G_*G_);
  k_buildw<<<NG_, 64, 0, stream>>>(W_hh, W_ih, Wcat);
  k_pn<<<2, 256, 0, stream>>>(W_ih, Pn);
  k_prep<<<BS_/16, 256, 0, stream>>>(vf, mask, eoh, subs,
                                     ln_sub_g, ln_sub_b, Abuf, cpk);
  for (int r0 = 0; r0 < BS_; r0 += CH_){
    k_gemm<<<dim3(CH_/128, NG_/128), 256, 0, stream>>>(
        Abuf + (size_t)r0*KC_, Wcat, nullptr, ghc, KC_, NG_, 0);
    k_gruelem<<<CH_/4, 256, 0, stream>>>(ghc, Abuf, Pn, b_ih, b_hh, cpk, bufh0, r0);
  }
  k_gemm<<<dim3(BS_/128, 4), 256, 0, stream>>>(bufh0, W1h,  b1,  bufh1, G_, G_, 1);
  k_gemm<<<dim3(BS_/128, 4), 256, 0, stream>>>(bufh1, W2ah, b2a, bufh0, G_, G_, 1);
  k_gemm<<<dim3(BS_/128, 4), 256, 0, stream>>>(bufh0, W2bh, b2b, bufh1, G_, G_, 1);
  k_ln_score<<<BS_/32, 256, 0, stream>>>(bufh1, ln_pre_g, ln_pre_b, Ws, bs, scores);
  k_softmax<<<B_, 256, 0, stream>>>(scores, probs_out);
  k_spect<<<B_, 256, 0, stream>>>(peaks, probs_out, out);
}

// Round 5
// 817.259 us; speedup vs baseline: 4.6860x; 1.0019x over previous
//
#include <hip/hip_runtime.h>
#include <math.h>

#define B_ 16
#define A_ 32
#define G_ 512
#define S_ 4096
#define M_ 8
#define BS_ 65536
#define KC_ 640      // concat K: 512 normed + 100 OH + 28 pad
#define NG_ 1536

typedef _Float16 half8 __attribute__((ext_vector_type(8)));
typedef _Float16 half4v __attribute__((ext_vector_type(4)));
typedef _Float16 half2v __attribute__((ext_vector_type(2)));
typedef float floatx4 __attribute__((ext_vector_type(4)));

typedef const __attribute__((address_space(1))) void* gas_t;
typedef __attribute__((address_space(3))) void* las_t;

// ---------------- helpers ----------------
__device__ __forceinline__ float wave_sum_f(float v){
#pragma unroll
  for (int o = 32; o > 0; o >>= 1) v += __shfl_xor(v, o);
  return v;
}
__device__ __forceinline__ float wave_max_f(float v){
#pragma unroll
  for (int o = 32; o > 0; o >>= 1) v = fmaxf(v, __shfl_xor(v, o));
  return v;
}
__device__ __forceinline__ float sigmoidf_(float x){ return 1.f/(1.f+__expf(-x)); }
__device__ __forceinline__ float tanhf_(float x){ return 1.f - 2.f/(__expf(2.f*x)+1.f); }

// ---------------- K0a: fp32 -> fp16 convert (n % 4 == 0) --------------------
__global__ __launch_bounds__(256) void k_cvt(const float* __restrict__ s,
                                             _Float16* __restrict__ d, int n){
  int i = (blockIdx.x*256 + threadIdx.x)*4;
  if (i >= n) return;
  float4 v = *(const float4*)(s+i);
  half4v o; o[0]=(_Float16)v.x; o[1]=(_Float16)v.y; o[2]=(_Float16)v.z; o[3]=(_Float16)v.w;
  *(half4v*)(d+i) = o;
}

// ---------------- K0b: build Wcat[1536][640] = [W_hh | W_ih(r,z) | 0] -------
__global__ __launch_bounds__(64) void k_buildw(const float* __restrict__ Whh,
                                               const float* __restrict__ Wih,
                                               _Float16* __restrict__ Wcat){
  int j = blockIdx.x;
  for (int p = threadIdx.x; p < KC_; p += 64){
    float v = 0.f;
    if (p < 512) v = Whh[(size_t)j*512 + p];
    else if (p < 612 && j < 1024) v = Wih[(size_t)j*100 + (p - 512)];
    Wcat[(size_t)j*KC_ + p] = (_Float16)v;
  }
}

// ---------------- K0c: Pn[100][512] — transposed prefix table for i_n -------
__global__ __launch_bounds__(256) void k_pn(const float* __restrict__ Wih,
                                            float* __restrict__ Pn){
  int d = blockIdx.x*256 + threadIdx.x;
  if (d >= 512) return;
  const float* src = Wih + (size_t)(1024 + d)*100;
#pragma unroll
  for (int f = 0; f < 5; ++f){
    int off = f*20;
    float run = 0.f;
    for (int k = 0; k < 20; ++k){
      run += src[off + k];
      Pn[(size_t)(off + k)*512 + d] = run;
    }
  }
}

// ---------------- K1: MFMA prep — swvs GEMM + LN + counts + OH --------------
// grid (S_/128, B_) block 256 (4 waves). Block: 128 subsets of batch b.
// swvs[16s x 16g tile] = one mfma_16x16x32_f16 (K=32=A_).
__global__ __launch_bounds__(256) void k_prep_mfma(
    const float* __restrict__ vf, const float* __restrict__ mask,
    const float* __restrict__ eoh, const float* __restrict__ subs,
    const float* __restrict__ ln_g, const float* __restrict__ ln_b,
    _Float16* __restrict__ Abuf, int* __restrict__ cpk){
  __shared__ _Float16 s_mvfT[G_*A_];   // [g][a], masked vf, 32 KB
  __shared__ _Float16 s_sm[128*A_];    // [s][a], raw subs, 8 KB
  __shared__ float s_m[A_];
  __shared__ float s_e[A_*5];
  __shared__ float s_ssum[128];
  __shared__ float s_red1[4][16];
  __shared__ float s_red2[4][16];
  int tid = threadIdx.x;
  int bx = blockIdx.x, b = blockIdx.y;
  int lane = tid & 63, w = tid >> 6;
  int q = lane >> 4, l15 = lane & 15;
  size_t row0 = (size_t)b*S_ + (size_t)bx*128;
  if (tid < A_)   s_m[tid] = mask[b*A_ + tid];
  if (tid < A_*5) s_e[tid] = eoh[b*A_*5 + tid];
  __syncthreads();
  // stage masked vf^T: thread owns a-pair p=(tid&15), g-seg (tid>>4)*32
  {
    int p = tid & 15, gseg = tid >> 4;
    float mk0 = s_m[2*p], mk1 = s_m[2*p+1];
    const float* v0 = vf + ((size_t)b*A_ + 2*p)*G_ + gseg*32;
    const float* v1 = v0 + G_;
#pragma unroll
    for (int i = 0; i < 32; ++i){
      int g = gseg*32 + i;
      half2v h; h[0] = (_Float16)(v0[i]*mk0); h[1] = (_Float16)(v1[i]*mk1);
      *(half2v*)(s_mvfT + g*A_ + 2*p) = h;
    }
  }
  // stage raw subs fp16
  {
    int s = tid >> 1, hh = tid & 1;
    const float* sp = subs + (row0 + s)*A_ + hh*16;
#pragma unroll
    for (int i = 0; i < 16; i += 2){
      half2v h; h[0] = (_Float16)sp[i]; h[1] = (_Float16)sp[i+1];
      *(half2v*)(s_sm + s*A_ + hh*16 + i) = h;
    }
  }
  __syncthreads();
  // counts / ssum / cpk / thermometer-OH (threads 0..127)
  if (tid < 128){
    int s = tid;
    float ssum = 0.f, c0=0.f, c1=0.f, c2=0.f, c3=0.f, c4=0.f;
#pragma unroll
    for (int a = 0; a < A_; ++a){
      float v = (float)s_sm[s*A_ + a];
      ssum += v * s_m[a];
      c0 += v * s_e[a*5+0]; c1 += v * s_e[a*5+1]; c2 += v * s_e[a*5+2];
      c3 += v * s_e[a*5+3]; c4 += v * s_e[a*5+4];
    }
    int cc[5];
    cc[0] = min(max((int)(c0+0.5f),0),19); cc[1] = min(max((int)(c1+0.5f),0),19);
    cc[2] = min(max((int)(c2+0.5f),0),19); cc[3] = min(max((int)(c3+0.5f),0),19);
    cc[4] = min(max((int)(c4+0.5f),0),19);
    cpk[row0 + s] = cc[0] | (cc[1]<<6) | (cc[2]<<12) | (cc[3]<<18) | (cc[4]<<24);
    s_ssum[s] = ssum;
    _Float16* dst = Abuf + (row0 + s)*KC_ + 512;
#pragma unroll
    for (int t = 0; t < 16; ++t){
      half8 hv;
#pragma unroll
      for (int u = 0; u < 8; ++u){
        int k = t*8 + u;
        float v = 0.f;
        if (k < 100){ int f = k/20, l = k - f*20; v = (l <= cc[f]) ? 1.f : 0.f; }
        hv[u] = (_Float16)v;
      }
      *(half8*)(dst + t*8) = hv;
    }
  }
  // B-fragments (masked vf^T rows = g) + LN params; wave w owns g in [w*128, w*128+128)
  half8 bf[8]; float lng[8], lnb[8];
#pragma unroll
  for (int t = 0; t < 8; ++t){
    int g = w*128 + t*16 + l15;
    bf[t] = *(const half8*)(s_mvfT + g*A_ + q*8);
    lng[t] = ln_g[g]; lnb[t] = ln_b[g];
  }
  __syncthreads();   // s_ssum ready
  for (int gi = 0; gi < 8; ++gi){
    half8 af = *(const half8*)(s_sm + (gi*16 + l15)*A_ + q*8);
    floatx4 c[8];
#pragma unroll
    for (int t = 0; t < 8; ++t){
      floatx4 z = {0.f, 0.f, 0.f, 0.f};
      c[t] = __builtin_amdgcn_mfma_f32_16x16x32_f16(af, bf[t], z, 0, 0, 0);
    }
    float p1[4] = {0.f,0.f,0.f,0.f}, p2[4] = {0.f,0.f,0.f,0.f};
#pragma unroll
    for (int t = 0; t < 8; ++t)
#pragma unroll
      for (int r = 0; r < 4; ++r){ float v = c[t][r]; p1[r] += v; p2[r] += v*v; }
#pragma unroll
    for (int off = 1; off < 16; off <<= 1)
#pragma unroll
      for (int r = 0; r < 4; ++r){
        p1[r] += __shfl_xor(p1[r], off);
        p2[r] += __shfl_xor(p2[r], off);
      }
    if (l15 == 0){
#pragma unroll
      for (int r = 0; r < 4; ++r){ s_red1[w][q*4+r] = p1[r]; s_red2[w][q*4+r] = p2[r]; }
    }
    __syncthreads();
#pragma unroll
    for (int r = 0; r < 4; ++r){
      int sl = gi*16 + q*4 + r;
      int rr = q*4 + r;
      float t1 = s_red1[0][rr] + s_red1[1][rr] + s_red1[2][rr] + s_red1[3][rr];
      float t2 = s_red2[0][rr] + s_red2[1][rr] + s_red2[2][rr] + s_red2[3][rr];
      float inv = 1.f/(s_ssum[sl] + 1e-4f);
      float mu = t1*inv*(1.f/512.f);
      float var = t2*inv*inv*(1.f/512.f) - mu*mu;
      float rs = rsqrtf(var + 1e-5f);
      _Float16* orow = Abuf + (row0 + sl)*KC_;
#pragma unroll
      for (int t = 0; t < 8; ++t){
        float o = (c[t][r]*inv - mu)*rs*lng[t] + lnb[t];
        orow[w*128 + t*16 + l15] = (_Float16)o;
      }
    }
    __syncthreads();
  }
}

// ---------------- K2: fused gh GEMM (3 gates) + GRU elementwise -------------
// grid (BS/128, 512/64). Block tile: M=128 x 64 d-dims x 3 gates. BK=32.
// Waves 2x2: wave tile 64m x 32d x 3 gates (acc 96 f32).
__global__ __launch_bounds__(256) void k_gru_fused(
    const _Float16* __restrict__ Abuf, const _Float16* __restrict__ Wcat,
    const float* __restrict__ Pn, const float* __restrict__ bih,
    const float* __restrict__ bhh, const int* __restrict__ cpk,
    _Float16* __restrict__ H){
  __shared__ _Float16 smA[128*32];   // 8 KB
  __shared__ _Float16 smB[192*32];   // 12 KB
  int tid = threadIdx.x;
  int lane = tid & 63, wvid = tid >> 6;
  int wm = wvid & 1, wn = wvid >> 1;
  int q = lane >> 4, l15 = lane & 15;
  int m0 = blockIdx.x*128, n0 = blockIdx.y*64;
  floatx4 acc[3][4][2] = {};
  int offA[4], offB[3][2];
#pragma unroll
  for (int i = 0; i < 4; ++i){
    int r = wm*64 + i*16 + l15;
    offA[i] = (r*4 + (q ^ ((r>>2)&3)))*8;
  }
#pragma unroll
  for (int g = 0; g < 3; ++g)
#pragma unroll
    for (int j = 0; j < 2; ++j){
      int rb = g*64 + wn*32 + j*16 + l15;
      offB[g][j] = (rb*4 + (q ^ ((rb>>2)&3)))*8;
    }
  const _Float16* gA[2]; int sA_[2];
#pragma unroll
  for (int t = 0; t < 2; ++t){
    int seg = wvid*2 + t;
    int u = seg*64 + lane;
    int r = u >> 2, c = (u & 3) ^ ((r >> 2) & 3);
    gA[t] = Abuf + (size_t)(m0 + r)*KC_ + c*8;
    sA_[t] = seg*512;
  }
  const _Float16* gB[3]; int sB_[3];
#pragma unroll
  for (int t = 0; t < 3; ++t){
    int seg = wvid*3 + t;
    int u = seg*64 + lane;
    int rb = u >> 2, c = (u & 3) ^ ((rb >> 2) & 3);
    int grow = (rb >> 6)*512 + n0 + (rb & 63);
    gB[t] = Wcat + (size_t)grow*KC_ + c*8;
    sB_[t] = seg*512;
  }
  for (int kc = 0; kc < KC_; kc += 32){
#pragma unroll
    for (int t = 0; t < 2; ++t)
      __builtin_amdgcn_global_load_lds((gas_t)(gA[t] + kc), (las_t)(smA + sA_[t]), 16, 0, 0);
#pragma unroll
    for (int t = 0; t < 3; ++t)
      __builtin_amdgcn_global_load_lds((gas_t)(gB[t] + kc), (las_t)(smB + sB_[t]), 16, 0, 0);
    __syncthreads();
    half8 af[4], bfv[3][2];
#pragma unroll
    for (int i = 0; i < 4; ++i) af[i] = *(const half8*)(smA + offA[i]);
#pragma unroll
    for (int g = 0; g < 3; ++g)
#pragma unroll
      for (int j = 0; j < 2; ++j) bfv[g][j] = *(const half8*)(smB + offB[g][j]);
#pragma unroll
    for (int g = 0; g < 3; ++g)
#pragma unroll
      for (int i = 0; i < 4; ++i)
#pragma unroll
        for (int j = 0; j < 2; ++j)
          acc[g][i][j] = __builtin_amdgcn_mfma_f32_16x16x32_f16(af[i], bfv[g][j], acc[g][i][j], 0, 0, 0);
    __syncthreads();
  }
  // epilogue: coalesced Pn lookups + GRU math + highway
  int dj[2]; float br[2], bz[2], bnh[2], bni[2];
#pragma unroll
  for (int j = 0; j < 2; ++j){
    int d = n0 + wn*32 + j*16 + l15;
    dj[j] = d;
    br[j]  = bih[d] + bhh[d];
    bz[j]  = bih[512+d] + bhh[512+d];
    bnh[j] = bhh[1024+d];
    bni[j] = bih[1024+d];
  }
#pragma unroll
  for (int i = 0; i < 4; ++i){
#pragma unroll
    for (int r = 0; r < 4; ++r){
      int m = m0 + wm*64 + i*16 + q*4 + r;
      int cp = cpk[m];
      int k0 =  (cp      ) & 63;
      int k1 = ((cp >> 6 ) & 63) + 20;
      int k2 = ((cp >> 12) & 63) + 40;
      int k3 = ((cp >> 18) & 63) + 60;
      int k4 = ((cp >> 24) & 63) + 80;
#pragma unroll
      for (int j = 0; j < 2; ++j){
        int d = dj[j];
        float in_ = bni[j] + Pn[(size_t)k0*512 + d] + Pn[(size_t)k1*512 + d]
                  + Pn[(size_t)k2*512 + d] + Pn[(size_t)k3*512 + d]
                  + Pn[(size_t)k4*512 + d];
        float gr = acc[0][i][j][r] + br[j];
        float gz = acc[1][i][j][r] + bz[j];
        float hn = acc[2][i][j][r] + bnh[j];
        float rrv = sigmoidf_(gr);
        float zz  = sigmoidf_(gz);
        float nn  = tanhf_(in_ + rrv*hn);
        float hp = (float)Abuf[(size_t)m*KC_ + d];
        H[(size_t)m*G_ + d] = (_Float16)((1.f-zz)*nn + zz*hp);
      }
    }
  }
}

// ---------------- K3: generic fp16 MFMA GEMM  Out = [relu](A @ W^T + bias) --
__global__ __launch_bounds__(256) void k_gemm(
    const _Float16* __restrict__ A, const _Float16* __restrict__ W,
    const float* __restrict__ bias, _Float16* __restrict__ Out,
    int K, int N, int relu){
  __shared__ _Float16 smA[128*32];
  __shared__ _Float16 smB[128*32];
  int tid = threadIdx.x;
  int lane = tid & 63, wvid = tid >> 6;
  int wm = wvid & 1, wn = wvid >> 1;
  int q = lane >> 4, l15 = lane & 15;
  int m0 = blockIdx.x*128, n0 = blockIdx.y*128;
  floatx4 acc[4][4] = {};
  int offA[4], offB[4];
#pragma unroll
  for (int i = 0; i < 4; ++i){
    int r = wm*64 + i*16 + l15;
    offA[i] = (r*4 + (q ^ ((r>>2)&3)))*8;
    int rb = wn*64 + i*16 + l15;
    offB[i] = (rb*4 + (q ^ ((rb>>2)&3)))*8;
  }
  int uA[2];
  const _Float16 *gA[2], *gB[2];
#pragma unroll
  for (int t = 0; t < 2; ++t){
    int seg = wvid*2 + t;
    int u = seg*64 + lane;
    int r = u >> 2, c = (u & 3) ^ ((r >> 2) & 3);
    uA[t] = seg;
    gA[t] = A + (size_t)(m0 + r)*K + c*8;
    gB[t] = W + (size_t)(n0 + r)*K + c*8;
  }
  for (int kc = 0; kc < K; kc += 32){
#pragma unroll
    for (int t = 0; t < 2; ++t){
      __builtin_amdgcn_global_load_lds((gas_t)(gA[t] + kc), (las_t)(smA + uA[t]*512), 16, 0, 0);
      __builtin_amdgcn_global_load_lds((gas_t)(gB[t] + kc), (las_t)(smB + uA[t]*512), 16, 0, 0);
    }
    __syncthreads();
    half8 af[4], bfv[4];
#pragma unroll
    for (int i = 0; i < 4; ++i) af[i] = *(const half8*)(smA + offA[i]);
#pragma unroll
    for (int j = 0; j < 4; ++j) bfv[j] = *(const half8*)(smB + offB[j]);
#pragma unroll
    for (int i = 0; i < 4; ++i)
#pragma unroll
      for (int j = 0; j < 4; ++j)
        acc[i][j] = __builtin_amdgcn_mfma_f32_16x16x32_f16(af[i], bfv[j], acc[i][j], 0, 0, 0);
    __syncthreads();
  }
#pragma unroll
  for (int j = 0; j < 4; ++j){
    int n = n0 + wn*64 + j*16 + l15;
    float bv = bias ? bias[n] : 0.f;
#pragma unroll
    for (int i = 0; i < 4; ++i){
#pragma unroll
      for (int r = 0; r < 4; ++r){
        int m = m0 + wm*64 + i*16 + q*4 + r;
        float o = acc[i][j][r] + bv;
        if (relu) o = fmaxf(o, 0.f);
        Out[(size_t)m*N + n] = (_Float16)o;
      }
    }
  }
}

// ---------------- K4: final LN + score (fp16 in, fp32 out) ------------------
__global__ __launch_bounds__(256) void k_ln_score(
    const _Float16* __restrict__ X, const float* __restrict__ g,
    const float* __restrict__ bta, const float* __restrict__ Ws,
    const float* __restrict__ bs, float* __restrict__ scores){
  int tid = threadIdx.x, lane = tid & 63, wv = tid >> 6;
  size_t row0 = (size_t)blockIdx.x*32 + wv*8;
  int e0 = lane*8;
  float wv_[8], gv[8], bv[8];
  *(float4*)(wv_ ) = *(const float4*)(Ws + e0);
  *(float4*)(wv_+4) = *(const float4*)(Ws + e0 + 4);
  *(float4*)(gv  ) = *(const float4*)(g + e0);
  *(float4*)(gv+4) = *(const float4*)(g + e0 + 4);
  *(float4*)(bv  ) = *(const float4*)(bta + e0);
  *(float4*)(bv+4) = *(const float4*)(bta + e0 + 4);
  float bsv = bs[0];
  for (int rr = 0; rr < 8; ++rr){
    size_t row = row0 + rr;
    half8 hx = *(const half8*)(X + row*G_ + e0);
    float xv[8];
#pragma unroll
    for (int t = 0; t < 8; ++t) xv[t] = (float)hx[t];
    float s1 = 0.f, s2 = 0.f;
#pragma unroll
    for (int t = 0; t < 8; ++t){ s1 += xv[t]; s2 += xv[t]*xv[t]; }
    s1 = wave_sum_f(s1); s2 = wave_sum_f(s2);
    float mu = s1*(1.f/512.f);
    float var = s2*(1.f/512.f) - mu*mu;
    float rs = rsqrtf(var + 1e-5f);
    float sc = 0.f;
#pragma unroll
    for (int t = 0; t < 8; ++t) sc += ((xv[t]-mu)*rs*gv[t] + bv[t])*wv_[t];
    sc = wave_sum_f(sc);
    if (lane == 0) scores[row] = sc + bsv;
  }
}

// ---------------- K5: softmax over S per batch ------------------------------
__global__ __launch_bounds__(256) void k_softmax(
    const float* __restrict__ scores, float* __restrict__ probs){
  __shared__ float red[4];
  int b = blockIdx.x, tid = threadIdx.x, lane = tid & 63, wv = tid >> 6;
  const float* sp = scores + (size_t)b*S_;
  float mx = -1e30f;
  for (int i = tid; i < S_; i += 256) mx = fmaxf(mx, sp[i]);
  mx = wave_max_f(mx);
  if (lane == 0) red[wv] = mx;
  __syncthreads();
  mx = fmaxf(fmaxf(red[0], red[1]), fmaxf(red[2], red[3]));
  __syncthreads();
  float sum = 0.f;
  for (int i = tid; i < S_; i += 256) sum += __expf(sp[i]-mx);
  sum = wave_sum_f(sum);
  if (lane == 0) red[wv] = sum;
  __syncthreads();
  sum = red[0]+red[1]+red[2]+red[3];
  float inv = 1.f/sum;
  for (int i = tid; i < S_; i += 256)
    probs[(size_t)b*S_ + i] = __expf(sp[i]-mx)*inv;
}

// ---------------- K6: spectrum scatter --------------------------------------
__global__ __launch_bounds__(256) void k_spect(
    const float* __restrict__ peaks, const float* __restrict__ probs,
    float* __restrict__ spect){
  __shared__ float bins[512];
  int b = blockIdx.x, tid = threadIdx.x;
  bins[tid] = 0.f; bins[tid+256] = 0.f;
  __syncthreads();
  for (int i = tid; i < S_*M_; i += 256){
    int s = i >> 3, m = i & 7;
    const float* pk = peaks + (((size_t)b*S_ + s)*M_ + m)*2;
    float mass = pk[0], inten = pk[1];
    float p = probs[(size_t)b*S_ + s];
    int bin = (int)rintf(mass);
    bin = min(max(bin, 0), 511);
    atomicAdd(&bins[bin], inten*p);
  }
  __syncthreads();
  spect[(size_t)b*512 + tid]       = bins[tid];
  spect[(size_t)b*512 + tid + 256] = bins[tid+256];
}

// ---------------- launcher --------------------------------------------------
extern "C" void kernel_launch(void* const* d_in, const int* in_sizes, int n_in,
                              void* d_out, int out_size, void* d_ws, size_t ws_size,
                              hipStream_t stream) {
  const float* vf       = (const float*)d_in[0];
  const float* mask     = (const float*)d_in[1];
  const float* eoh      = (const float*)d_in[2];
  const float* subs     = (const float*)d_in[4];
  const float* peaks    = (const float*)d_in[5];
  const float* ln_sub_g = (const float*)d_in[6];
  const float* ln_sub_b = (const float*)d_in[7];
  const float* W_ih     = (const float*)d_in[8];
  const float* W_hh     = (const float*)d_in[9];
  const float* b_ih     = (const float*)d_in[10];
  const float* b_hh     = (const float*)d_in[11];
  const float* W1       = (const float*)d_in[12];
  const float* b1       = (const float*)d_in[13];
  const float* W2a      = (const float*)d_in[14];
  const float* b2a      = (const float*)d_in[15];
  const float* W2b      = (const float*)d_in[16];
  const float* b2b      = (const float*)d_in[17];
  const float* ln_pre_g = (const float*)d_in[18];
  const float* ln_pre_b = (const float*)d_in[19];
  const float* Ws       = (const float*)d_in[20];
  const float* bs       = (const float*)d_in[21];
  float* out = (float*)d_out;            // [0,8192) spect, [8192,73728) probs
  float* probs_out = out + (size_t)B_*512;

  // workspace carve — total ~155 MB (ws >= ~206 MB proven in round 3)
  char* w = (char*)d_ws;
  float* Pn = (float*)w;         w += (size_t)100*512*4;
  int*   cpk = (int*)w;          w += (size_t)BS_*4;
  float* scores = (float*)w;     w += (size_t)BS_*4;
  _Float16* Wcat = (_Float16*)w; w += (size_t)NG_*KC_*2;
  _Float16* W1h  = (_Float16*)w; w += (size_t)G_*G_*2;
  _Float16* W2ah = (_Float16*)w; w += (size_t)G_*G_*2;
  _Float16* W2bh = (_Float16*)w; w += (size_t)G_*G_*2;
  _Float16* Abuf = (_Float16*)w; w += (size_t)BS_*KC_*2;       // 84 MB
  _Float16* bufh0 = (_Float16*)w;                              // 67 MB (H)
  _Float16* bufh1 = Abuf;        // FF ping-pong reuses A region (84 >= 67 MB)

  k_cvt<<<(G_*G_/4+255)/256, 256, 0, stream>>>(W1,  W1h,  G_*G_);
  k_cvt<<<(G_*G_/4+255)/256, 256, 0, stream>>>(W2a, W2ah, G_*G_);
  k_cvt<<<(G_*G_/4+255)/256, 256, 0, stream>>>(W2b, W2bh, G_*G_);
  k_buildw<<<NG_, 64, 0, stream>>>(W_hh, W_ih, Wcat);
  k_pn<<<2, 256, 0, stream>>>(W_ih, Pn);
  k_prep_mfma<<<dim3(S_/128, B_), 256, 0, stream>>>(vf, mask, eoh, subs,
                                                    ln_sub_g, ln_sub_b, Abuf, cpk);
  k_gru_fused<<<dim3(BS_/128, 8), 256, 0, stream>>>(Abuf, Wcat, Pn, b_ih, b_hh,
                                                    cpk, bufh0);
  k_gemm<<<dim3(BS_/128, 4), 256, 0, stream>>>(bufh0, W1h,  b1,  bufh1, G_, G_, 1);
  k_gemm<<<dim3(BS_/128, 4), 256, 0, stream>>>(bufh1, W2ah, b2a, bufh0, G_, G_, 1);
  k_gemm<<<dim3(BS_/128, 4), 256, 0, stream>>>(bufh0, W2bh, b2b, bufh1, G_, G_, 1);
  k_ln_score<<<BS_/32, 256, 0, stream>>>(bufh1, ln_pre_g, ln_pre_b, Ws, bs, scores);
  k_softmax<<<B_, 256, 0, stream>>>(scores, probs_out);
  k_spect<<<B_, 256, 0, stream>>>(peaks, probs_out, out);
}

// Round 6
// 644.008 us; speedup vs baseline: 5.9466x; 1.2690x over previous
//
#include <hip/hip_runtime.h>
#include <math.h>

#define B_ 16
#define A_ 32
#define G_ 512
#define S_ 4096
#define M_ 8
#define BS_ 65536
#define KC_ 640      // concat K: 512 normed + 100 OH + 28 pad
#define NG_ 1536

typedef _Float16 half8 __attribute__((ext_vector_type(8)));
typedef _Float16 half4v __attribute__((ext_vector_type(4)));
typedef _Float16 half2v __attribute__((ext_vector_type(2)));
typedef float floatx4 __attribute__((ext_vector_type(4)));

typedef const __attribute__((address_space(1))) void* gas_t;
typedef __attribute__((address_space(3))) void* las_t;

// ---------------- helpers ----------------
__device__ __forceinline__ float wave_sum_f(float v){
#pragma unroll
  for (int o = 32; o > 0; o >>= 1) v += __shfl_xor(v, o);
  return v;
}
__device__ __forceinline__ float wave_max_f(float v){
#pragma unroll
  for (int o = 32; o > 0; o >>= 1) v = fmaxf(v, __shfl_xor(v, o));
  return v;
}
__device__ __forceinline__ float sigmoidf_(float x){ return 1.f/(1.f+__expf(-x)); }
__device__ __forceinline__ float tanhf_(float x){ return 1.f - 2.f/(__expf(2.f*x)+1.f); }

// ---------------- K0a: fp32 -> fp16 convert (n % 4 == 0) --------------------
__global__ __launch_bounds__(256) void k_cvt(const float* __restrict__ s,
                                             _Float16* __restrict__ d, int n){
  int i = (blockIdx.x*256 + threadIdx.x)*4;
  if (i >= n) return;
  float4 v = *(const float4*)(s+i);
  half4v o; o[0]=(_Float16)v.x; o[1]=(_Float16)v.y; o[2]=(_Float16)v.z; o[3]=(_Float16)v.w;
  *(half4v*)(d+i) = o;
}

// ---------------- K0b: build Wcat[1536][640] = [W_hh | W_ih(r,z) | 0] -------
__global__ __launch_bounds__(64) void k_buildw(const float* __restrict__ Whh,
                                               const float* __restrict__ Wih,
                                               _Float16* __restrict__ Wcat){
  int j = blockIdx.x;
  for (int p = threadIdx.x; p < KC_; p += 64){
    float v = 0.f;
    if (p < 512) v = Whh[(size_t)j*512 + p];
    else if (p < 612 && j < 1024) v = Wih[(size_t)j*100 + (p - 512)];
    Wcat[(size_t)j*KC_ + p] = (_Float16)v;
  }
}

// ---------------- K0c: Pn[100][512] — transposed prefix table for i_n -------
__global__ __launch_bounds__(256) void k_pn(const float* __restrict__ Wih,
                                            float* __restrict__ Pn){
  int d = blockIdx.x*256 + threadIdx.x;
  if (d >= 512) return;
  const float* src = Wih + (size_t)(1024 + d)*100;
#pragma unroll
  for (int f = 0; f < 5; ++f){
    int off = f*20;
    float run = 0.f;
    for (int k = 0; k < 20; ++k){
      run += src[off + k];
      Pn[(size_t)(off + k)*512 + d] = run;
    }
  }
}

// ---------------- K1: MFMA prep — swvs GEMM + LN + counts + OH --------------
__global__ __launch_bounds__(256) void k_prep_mfma(
    const float* __restrict__ vf, const float* __restrict__ mask,
    const float* __restrict__ eoh, const float* __restrict__ subs,
    const float* __restrict__ ln_g, const float* __restrict__ ln_b,
    _Float16* __restrict__ Abuf, int* __restrict__ cpk){
  __shared__ _Float16 s_mvfT[G_*A_];   // [g][a], masked vf, 32 KB
  __shared__ _Float16 s_sm[128*A_];    // [s][a], raw subs, 8 KB
  __shared__ float s_m[A_];
  __shared__ float s_e[A_*5];
  __shared__ float s_ssum[128];
  __shared__ float s_red1[4][16];
  __shared__ float s_red2[4][16];
  int tid = threadIdx.x;
  int bx = blockIdx.x, b = blockIdx.y;
  int lane = tid & 63, w = tid >> 6;
  int q = lane >> 4, l15 = lane & 15;
  size_t row0 = (size_t)b*S_ + (size_t)bx*128;
  if (tid < A_)   s_m[tid] = mask[b*A_ + tid];
  if (tid < A_*5) s_e[tid] = eoh[b*A_*5 + tid];
  __syncthreads();
  {
    int p = tid & 15, gseg = tid >> 4;
    float mk0 = s_m[2*p], mk1 = s_m[2*p+1];
    const float* v0 = vf + ((size_t)b*A_ + 2*p)*G_ + gseg*32;
    const float* v1 = v0 + G_;
#pragma unroll
    for (int i = 0; i < 32; ++i){
      int g = gseg*32 + i;
      half2v h; h[0] = (_Float16)(v0[i]*mk0); h[1] = (_Float16)(v1[i]*mk1);
      *(half2v*)(s_mvfT + g*A_ + 2*p) = h;
    }
  }
  {
    int s = tid >> 1, hh = tid & 1;
    const float* sp = subs + (row0 + s)*A_ + hh*16;
#pragma unroll
    for (int i = 0; i < 16; i += 2){
      half2v h; h[0] = (_Float16)sp[i]; h[1] = (_Float16)sp[i+1];
      *(half2v*)(s_sm + s*A_ + hh*16 + i) = h;
    }
  }
  __syncthreads();
  if (tid < 128){
    int s = tid;
    float ssum = 0.f, c0=0.f, c1=0.f, c2=0.f, c3=0.f, c4=0.f;
#pragma unroll
    for (int a = 0; a < A_; ++a){
      float v = (float)s_sm[s*A_ + a];
      ssum += v * s_m[a];
      c0 += v * s_e[a*5+0]; c1 += v * s_e[a*5+1]; c2 += v * s_e[a*5+2];
      c3 += v * s_e[a*5+3]; c4 += v * s_e[a*5+4];
    }
    int cc[5];
    cc[0] = min(max((int)(c0+0.5f),0),19); cc[1] = min(max((int)(c1+0.5f),0),19);
    cc[2] = min(max((int)(c2+0.5f),0),19); cc[3] = min(max((int)(c3+0.5f),0),19);
    cc[4] = min(max((int)(c4+0.5f),0),19);
    cpk[row0 + s] = cc[0] | (cc[1]<<6) | (cc[2]<<12) | (cc[3]<<18) | (cc[4]<<24);
    s_ssum[s] = ssum;
    _Float16* dst = Abuf + (row0 + s)*KC_ + 512;
#pragma unroll
    for (int t = 0; t < 16; ++t){
      half8 hv;
#pragma unroll
      for (int u = 0; u < 8; ++u){
        int k = t*8 + u;
        float v = 0.f;
        if (k < 100){ int f = k/20, l = k - f*20; v = (l <= cc[f]) ? 1.f : 0.f; }
        hv[u] = (_Float16)v;
      }
      *(half8*)(dst + t*8) = hv;
    }
  }
  half8 bf[8]; float lng[8], lnb[8];
#pragma unroll
  for (int t = 0; t < 8; ++t){
    int g = w*128 + t*16 + l15;
    bf[t] = *(const half8*)(s_mvfT + g*A_ + q*8);
    lng[t] = ln_g[g]; lnb[t] = ln_b[g];
  }
  __syncthreads();
  for (int gi = 0; gi < 8; ++gi){
    half8 af = *(const half8*)(s_sm + (gi*16 + l15)*A_ + q*8);
    floatx4 c[8];
#pragma unroll
    for (int t = 0; t < 8; ++t){
      floatx4 z = {0.f, 0.f, 0.f, 0.f};
      c[t] = __builtin_amdgcn_mfma_f32_16x16x32_f16(af, bf[t], z, 0, 0, 0);
    }
    float p1[4] = {0.f,0.f,0.f,0.f}, p2[4] = {0.f,0.f,0.f,0.f};
#pragma unroll
    for (int t = 0; t < 8; ++t)
#pragma unroll
      for (int r = 0; r < 4; ++r){ float v = c[t][r]; p1[r] += v; p2[r] += v*v; }
#pragma unroll
    for (int off = 1; off < 16; off <<= 1)
#pragma unroll
      for (int r = 0; r < 4; ++r){
        p1[r] += __shfl_xor(p1[r], off);
        p2[r] += __shfl_xor(p2[r], off);
      }
    if (l15 == 0){
#pragma unroll
      for (int r = 0; r < 4; ++r){ s_red1[w][q*4+r] = p1[r]; s_red2[w][q*4+r] = p2[r]; }
    }
    __syncthreads();
#pragma unroll
    for (int r = 0; r < 4; ++r){
      int sl = gi*16 + q*4 + r;
      int rr = q*4 + r;
      float t1 = s_red1[0][rr] + s_red1[1][rr] + s_red1[2][rr] + s_red1[3][rr];
      float t2 = s_red2[0][rr] + s_red2[1][rr] + s_red2[2][rr] + s_red2[3][rr];
      float inv = 1.f/(s_ssum[sl] + 1e-4f);
      float mu = t1*inv*(1.f/512.f);
      float var = t2*inv*inv*(1.f/512.f) - mu*mu;
      float rs = rsqrtf(var + 1e-5f);
      _Float16* orow = Abuf + (row0 + sl)*KC_;
#pragma unroll
      for (int t = 0; t < 8; ++t){
        float o = (c[t][r]*inv - mu)*rs*lng[t] + lnb[t];
        orow[w*128 + t*16 + l15] = (_Float16)o;
      }
    }
    __syncthreads();
  }
}

// ---------------- K2: fused gh GEMM (3 gates) + GRU elementwise -------------
// grid (8, BS/64): x = n-tile (64 d), y = m-tile (64 rows). n-major dispatch
// -> the 8 n-blocks of an m-tile are adjacent in time (A-tile L2 reuse).
// Waves 2x2: wave tile 32m x (32d x 3 gates) -> acc 48 f32 (12 MFMA/K-iter).
__global__ __launch_bounds__(256) void k_gru_fused(
    const _Float16* __restrict__ Abuf, const _Float16* __restrict__ Wcat,
    const float* __restrict__ Pn, const float* __restrict__ bih,
    const float* __restrict__ bhh, const int* __restrict__ cpk,
    _Float16* __restrict__ H){
  __shared__ _Float16 smA[64*32];    // 4 KB
  __shared__ _Float16 smB[192*32];   // 12 KB
  int tid = threadIdx.x;
  int lane = tid & 63, wvid = tid >> 6;
  int wm = wvid & 1, wn = wvid >> 1;
  int q = lane >> 4, l15 = lane & 15;
  int n0 = blockIdx.x*64, m0 = blockIdx.y*64;
  floatx4 acc[3][2][2] = {};
  int offA[2], offB[3][2];
#pragma unroll
  for (int i = 0; i < 2; ++i){
    int r = wm*32 + i*16 + l15;
    offA[i] = (r*4 + (q ^ ((r>>2)&3)))*8;
  }
#pragma unroll
  for (int g = 0; g < 3; ++g)
#pragma unroll
    for (int j = 0; j < 2; ++j){
      int rb = g*64 + wn*32 + j*16 + l15;
      offB[g][j] = (rb*4 + (q ^ ((rb>>2)&3)))*8;
    }
  // staging: A 256 units (4 segs), B 768 units (12 segs); wave: 1 A + 3 B segs
  const _Float16* gA; int sAo;
  {
    int seg = wvid;
    int u = seg*64 + lane;
    int r = u >> 2, c = (u & 3) ^ ((r >> 2) & 3);
    gA = Abuf + (size_t)(m0 + r)*KC_ + c*8;
    sAo = seg*512;
  }
  const _Float16* gB[3]; int sBo[3];
#pragma unroll
  for (int t = 0; t < 3; ++t){
    int seg = wvid*3 + t;
    int u = seg*64 + lane;
    int rb = u >> 2, c = (u & 3) ^ ((rb >> 2) & 3);
    int grow = (rb >> 6)*512 + n0 + (rb & 63);
    gB[t] = Wcat + (size_t)grow*KC_ + c*8;
    sBo[t] = seg*512;
  }
  for (int kc = 0; kc < KC_; kc += 32){
    __builtin_amdgcn_global_load_lds((gas_t)(gA + kc), (las_t)(smA + sAo), 16, 0, 0);
#pragma unroll
    for (int t = 0; t < 3; ++t)
      __builtin_amdgcn_global_load_lds((gas_t)(gB[t] + kc), (las_t)(smB + sBo[t]), 16, 0, 0);
    __syncthreads();
    half8 af[2], bfv[3][2];
#pragma unroll
    for (int i = 0; i < 2; ++i) af[i] = *(const half8*)(smA + offA[i]);
#pragma unroll
    for (int g = 0; g < 3; ++g)
#pragma unroll
      for (int j = 0; j < 2; ++j) bfv[g][j] = *(const half8*)(smB + offB[g][j]);
#pragma unroll
    for (int g = 0; g < 3; ++g)
#pragma unroll
      for (int i = 0; i < 2; ++i)
#pragma unroll
        for (int j = 0; j < 2; ++j)
          acc[g][i][j] = __builtin_amdgcn_mfma_f32_16x16x32_f16(af[i], bfv[g][j], acc[g][i][j], 0, 0, 0);
    __syncthreads();
  }
  // epilogue: coalesced Pn lookups + GRU math + highway
  int dj[2]; float br[2], bz[2], bnh[2], bni[2];
#pragma unroll
  for (int j = 0; j < 2; ++j){
    int d = n0 + wn*32 + j*16 + l15;
    dj[j] = d;
    br[j]  = bih[d] + bhh[d];
    bz[j]  = bih[512+d] + bhh[512+d];
    bnh[j] = bhh[1024+d];
    bni[j] = bih[1024+d];
  }
#pragma unroll
  for (int i = 0; i < 2; ++i){
#pragma unroll
    for (int r = 0; r < 4; ++r){
      int m = m0 + wm*32 + i*16 + q*4 + r;
      int cp = cpk[m];
      int k0 =  (cp      ) & 63;
      int k1 = ((cp >> 6 ) & 63) + 20;
      int k2 = ((cp >> 12) & 63) + 40;
      int k3 = ((cp >> 18) & 63) + 60;
      int k4 = ((cp >> 24) & 63) + 80;
#pragma unroll
      for (int j = 0; j < 2; ++j){
        int d = dj[j];
        float in_ = bni[j] + Pn[(size_t)k0*512 + d] + Pn[(size_t)k1*512 + d]
                  + Pn[(size_t)k2*512 + d] + Pn[(size_t)k3*512 + d]
                  + Pn[(size_t)k4*512 + d];
        float gr = acc[0][i][j][r] + br[j];
        float gz = acc[1][i][j][r] + bz[j];
        float hn = acc[2][i][j][r] + bnh[j];
        float rrv = sigmoidf_(gr);
        float zz  = sigmoidf_(gz);
        float nn  = tanhf_(in_ + rrv*hn);
        float hp = (float)Abuf[(size_t)m*KC_ + d];
        H[(size_t)m*G_ + d] = (_Float16)((1.f-zz)*nn + zz*hp);
      }
    }
  }
}

// ---------------- K3: generic fp16 MFMA GEMM  Out = [relu](A @ W^T + bias) --
// grid (n-tiles, m-tiles): n-major dispatch for A-tile L2 reuse.
__global__ __launch_bounds__(256) void k_gemm(
    const _Float16* __restrict__ A, const _Float16* __restrict__ W,
    const float* __restrict__ bias, _Float16* __restrict__ Out,
    int K, int N, int relu){
  __shared__ _Float16 smA[128*32];
  __shared__ _Float16 smB[128*32];
  int tid = threadIdx.x;
  int lane = tid & 63, wvid = tid >> 6;
  int wm = wvid & 1, wn = wvid >> 1;
  int q = lane >> 4, l15 = lane & 15;
  int m0 = blockIdx.y*128, n0 = blockIdx.x*128;
  floatx4 acc[4][4] = {};
  int offA[4], offB[4];
#pragma unroll
  for (int i = 0; i < 4; ++i){
    int r = wm*64 + i*16 + l15;
    offA[i] = (r*4 + (q ^ ((r>>2)&3)))*8;
    int rb = wn*64 + i*16 + l15;
    offB[i] = (rb*4 + (q ^ ((rb>>2)&3)))*8;
  }
  int uA[2];
  const _Float16 *gA[2], *gB[2];
#pragma unroll
  for (int t = 0; t < 2; ++t){
    int seg = wvid*2 + t;
    int u = seg*64 + lane;
    int r = u >> 2, c = (u & 3) ^ ((r >> 2) & 3);
    uA[t] = seg;
    gA[t] = A + (size_t)(m0 + r)*K + c*8;
    gB[t] = W + (size_t)(n0 + r)*K + c*8;
  }
  for (int kc = 0; kc < K; kc += 32){
#pragma unroll
    for (int t = 0; t < 2; ++t){
      __builtin_amdgcn_global_load_lds((gas_t)(gA[t] + kc), (las_t)(smA + uA[t]*512), 16, 0, 0);
      __builtin_amdgcn_global_load_lds((gas_t)(gB[t] + kc), (las_t)(smB + uA[t]*512), 16, 0, 0);
    }
    __syncthreads();
    half8 af[4], bfv[4];
#pragma unroll
    for (int i = 0; i < 4; ++i) af[i] = *(const half8*)(smA + offA[i]);
#pragma unroll
    for (int j = 0; j < 4; ++j) bfv[j] = *(const half8*)(smB + offB[j]);
#pragma unroll
    for (int i = 0; i < 4; ++i)
#pragma unroll
      for (int j = 0; j < 4; ++j)
        acc[i][j] = __builtin_amdgcn_mfma_f32_16x16x32_f16(af[i], bfv[j], acc[i][j], 0, 0, 0);
    __syncthreads();
  }
#pragma unroll
  for (int j = 0; j < 4; ++j){
    int n = n0 + wn*64 + j*16 + l15;
    float bv = bias ? bias[n] : 0.f;
#pragma unroll
    for (int i = 0; i < 4; ++i){
#pragma unroll
      for (int r = 0; r < 4; ++r){
        int m = m0 + wm*64 + i*16 + q*4 + r;
        float o = acc[i][j][r] + bv;
        if (relu) o = fmaxf(o, 0.f);
        Out[(size_t)m*N + n] = (_Float16)o;
      }
    }
  }
}

// ---------------- K4: final LN + score (fp16 in, fp32 out) ------------------
__global__ __launch_bounds__(256) void k_ln_score(
    const _Float16* __restrict__ X, const float* __restrict__ g,
    const float* __restrict__ bta, const float* __restrict__ Ws,
    const float* __restrict__ bs, float* __restrict__ scores){
  int tid = threadIdx.x, lane = tid & 63, wv = tid >> 6;
  size_t row0 = (size_t)blockIdx.x*32 + wv*8;
  int e0 = lane*8;
  float wv_[8], gv[8], bv[8];
  *(float4*)(wv_ ) = *(const float4*)(Ws + e0);
  *(float4*)(wv_+4) = *(const float4*)(Ws + e0 + 4);
  *(float4*)(gv  ) = *(const float4*)(g + e0);
  *(float4*)(gv+4) = *(const float4*)(g + e0 + 4);
  *(float4*)(bv  ) = *(const float4*)(bta + e0);
  *(float4*)(bv+4) = *(const float4*)(bta + e0 + 4);
  float bsv = bs[0];
  for (int rr = 0; rr < 8; ++rr){
    size_t row = row0 + rr;
    half8 hx = *(const half8*)(X + row*G_ + e0);
    float xv[8];
#pragma unroll
    for (int t = 0; t < 8; ++t) xv[t] = (float)hx[t];
    float s1 = 0.f, s2 = 0.f;
#pragma unroll
    for (int t = 0; t < 8; ++t){ s1 += xv[t]; s2 += xv[t]*xv[t]; }
    s1 = wave_sum_f(s1); s2 = wave_sum_f(s2);
    float mu = s1*(1.f/512.f);
    float var = s2*(1.f/512.f) - mu*mu;
    float rs = rsqrtf(var + 1e-5f);
    float sc = 0.f;
#pragma unroll
    for (int t = 0; t < 8; ++t) sc += ((xv[t]-mu)*rs*gv[t] + bv[t])*wv_[t];
    sc = wave_sum_f(sc);
    if (lane == 0) scores[row] = sc + bsv;
  }
}

// ---------------- K5: softmax over S per batch ------------------------------
__global__ __launch_bounds__(256) void k_softmax(
    const float* __restrict__ scores, float* __restrict__ probs){
  __shared__ float red[4];
  int b = blockIdx.x, tid = threadIdx.x, lane = tid & 63, wv = tid >> 6;
  const float* sp = scores + (size_t)b*S_;
  float mx = -1e30f;
  for (int i = tid; i < S_; i += 256) mx = fmaxf(mx, sp[i]);
  mx = wave_max_f(mx);
  if (lane == 0) red[wv] = mx;
  __syncthreads();
  mx = fmaxf(fmaxf(red[0], red[1]), fmaxf(red[2], red[3]));
  __syncthreads();
  float sum = 0.f;
  for (int i = tid; i < S_; i += 256) sum += __expf(sp[i]-mx);
  sum = wave_sum_f(sum);
  if (lane == 0) red[wv] = sum;
  __syncthreads();
  sum = red[0]+red[1]+red[2]+red[3];
  float inv = 1.f/sum;
  for (int i = tid; i < S_; i += 256)
    probs[(size_t)b*S_ + i] = __expf(sp[i]-mx)*inv;
}

// ---------------- K6: spectrum scatter --------------------------------------
__global__ __launch_bounds__(256) void k_spect(
    const float* __restrict__ peaks, const float* __restrict__ probs,
    float* __restrict__ spect){
  __shared__ float bins[512];
  int b = blockIdx.x, tid = threadIdx.x;
  bins[tid] = 0.f; bins[tid+256] = 0.f;
  __syncthreads();
  for (int i = tid; i < S_*M_; i += 256){
    int s = i >> 3, m = i & 7;
    const float* pk = peaks + (((size_t)b*S_ + s)*M_ + m)*2;
    float mass = pk[0], inten = pk[1];
    float p = probs[(size_t)b*S_ + s];
    int bin = (int)rintf(mass);
    bin = min(max(bin, 0), 511);
    atomicAdd(&bins[bin], inten*p);
  }
  __syncthreads();
  spect[(size_t)b*512 + tid]       = bins[tid];
  spect[(size_t)b*512 + tid + 256] = bins[tid+256];
}

// ---------------- launcher --------------------------------------------------
extern "C" void kernel_launch(void* const* d_in, const int* in_sizes, int n_in,
                              void* d_out, int out_size, void* d_ws, size_t ws_size,
                              hipStream_t stream) {
  const float* vf       = (const float*)d_in[0];
  const float* mask     = (const float*)d_in[1];
  const float* eoh      = (const float*)d_in[2];
  const float* subs     = (const float*)d_in[4];
  const float* peaks    = (const float*)d_in[5];
  const float* ln_sub_g = (const float*)d_in[6];
  const float* ln_sub_b = (const float*)d_in[7];
  const float* W_ih     = (const float*)d_in[8];
  const float* W_hh     = (const float*)d_in[9];
  const float* b_ih     = (const float*)d_in[10];
  const float* b_hh     = (const float*)d_in[11];
  const float* W1       = (const float*)d_in[12];
  const float* b1       = (const float*)d_in[13];
  const float* W2a      = (const float*)d_in[14];
  const float* b2a      = (const float*)d_in[15];
  const float* W2b      = (const float*)d_in[16];
  const float* b2b      = (const float*)d_in[17];
  const float* ln_pre_g = (const float*)d_in[18];
  const float* ln_pre_b = (const float*)d_in[19];
  const float* Ws       = (const float*)d_in[20];
  const float* bs       = (const float*)d_in[21];
  float* out = (float*)d_out;            // [0,8192) spect, [8192,73728) probs
  float* probs_out = out + (size_t)B_*512;

  // workspace carve — total ~155 MB (ws >= ~206 MB proven in round 3)
  char* w = (char*)d_ws;
  float* Pn = (float*)w;         w += (size_t)100*512*4;
  int*   cpk = (int*)w;          w += (size_t)BS_*4;
  float* scores = (float*)w;     w += (size_t)BS_*4;
  _Float16* Wcat = (_Float16*)w; w += (size_t)NG_*KC_*2;
  _Float16* W1h  = (_Float16*)w; w += (size_t)G_*G_*2;
  _Float16* W2ah = (_Float16*)w; w += (size_t)G_*G_*2;
  _Float16* W2bh = (_Float16*)w; w += (size_t)G_*G_*2;
  _Float16* Abuf = (_Float16*)w; w += (size_t)BS_*KC_*2;       // 84 MB
  _Float16* bufh0 = (_Float16*)w;                              // 67 MB (H)
  _Float16* bufh1 = Abuf;        // FF ping-pong reuses A region (84 >= 67 MB)

  k_cvt<<<(G_*G_/4+255)/256, 256, 0, stream>>>(W1,  W1h,  G_*G_);
  k_cvt<<<(G_*G_/4+255)/256, 256, 0, stream>>>(W2a, W2ah, G_*G_);
  k_cvt<<<(G_*G_/4+255)/256, 256, 0, stream>>>(W2b, W2bh, G_*G_);
  k_buildw<<<NG_, 64, 0, stream>>>(W_hh, W_ih, Wcat);
  k_pn<<<2, 256, 0, stream>>>(W_ih, Pn);
  k_prep_mfma<<<dim3(S_/128, B_), 256, 0, stream>>>(vf, mask, eoh, subs,
                                                    ln_sub_g, ln_sub_b, Abuf, cpk);
  k_gru_fused<<<dim3(8, BS_/64), 256, 0, stream>>>(Abuf, Wcat, Pn, b_ih, b_hh,
                                                   cpk, bufh0);
  k_gemm<<<dim3(4, BS_/128), 256, 0, stream>>>(bufh0, W1h,  b1,  bufh1, G_, G_, 1);
  k_gemm<<<dim3(4, BS_/128), 256, 0, stream>>>(bufh1, W2ah, b2a, bufh0, G_, G_, 1);
  k_gemm<<<dim3(4, BS_/128), 256, 0, stream>>>(bufh0, W2bh, b2b, bufh1, G_, G_, 1);
  k_ln_score<<<BS_/32, 256, 0, stream>>>(bufh1, ln_pre_g, ln_pre_b, Ws, bs, scores);
  k_softmax<<<B_, 256, 0, stream>>>(scores, probs_out);
  k_spect<<<B_, 256, 0, stream>>>(peaks, probs_out, out);
}

// Round 7
// 541.594 us; speedup vs baseline: 7.0711x; 1.1891x over previous
//
#include <hip/hip_runtime.h>
#include <math.h>

#define B_ 16
#define A_ 32
#define G_ 512
#define S_ 4096
#define M_ 8
#define BS_ 65536
#define KC_ 640      // concat K: 512 normed + 100 OH + 28 pad
#define NG_ 1536

typedef _Float16 half8 __attribute__((ext_vector_type(8)));
typedef _Float16 half4v __attribute__((ext_vector_type(4)));
typedef _Float16 half2v __attribute__((ext_vector_type(2)));
typedef float floatx4 __attribute__((ext_vector_type(4)));

typedef const __attribute__((address_space(1))) void* gas_t;
typedef __attribute__((address_space(3))) void* las_t;

// ---------------- helpers ----------------
__device__ __forceinline__ float wave_sum_f(float v){
#pragma unroll
  for (int o = 32; o > 0; o >>= 1) v += __shfl_xor(v, o);
  return v;
}
__device__ __forceinline__ float wave_max_f(float v){
#pragma unroll
  for (int o = 32; o > 0; o >>= 1) v = fmaxf(v, __shfl_xor(v, o));
  return v;
}
__device__ __forceinline__ float sigmoidf_(float x){ return 1.f/(1.f+__expf(-x)); }
__device__ __forceinline__ float tanhf_(float x){ return 1.f - 2.f/(__expf(2.f*x)+1.f); }

// ---------------- K0a: fp32 -> fp16 convert (n % 4 == 0) --------------------
__global__ __launch_bounds__(256) void k_cvt(const float* __restrict__ s,
                                             _Float16* __restrict__ d, int n){
  int i = (blockIdx.x*256 + threadIdx.x)*4;
  if (i >= n) return;
  float4 v = *(const float4*)(s+i);
  half4v o; o[0]=(_Float16)v.x; o[1]=(_Float16)v.y; o[2]=(_Float16)v.z; o[3]=(_Float16)v.w;
  *(half4v*)(d+i) = o;
}

// ---------------- K0b: build Wcat[1536][640] = [W_hh | W_ih(r,z) | 0] -------
__global__ __launch_bounds__(64) void k_buildw(const float* __restrict__ Whh,
                                               const float* __restrict__ Wih,
                                               _Float16* __restrict__ Wcat){
  int j = blockIdx.x;
  for (int p = threadIdx.x; p < KC_; p += 64){
    float v = 0.f;
    if (p < 512) v = Whh[(size_t)j*512 + p];
    else if (p < 612 && j < 1024) v = Wih[(size_t)j*100 + (p - 512)];
    Wcat[(size_t)j*KC_ + p] = (_Float16)v;
  }
}

// ---------------- K0c: Pn[100][512] — transposed prefix table for i_n -------
__global__ __launch_bounds__(256) void k_pn(const float* __restrict__ Wih,
                                            float* __restrict__ Pn){
  int d = blockIdx.x*256 + threadIdx.x;
  if (d >= 512) return;
  const float* src = Wih + (size_t)(1024 + d)*100;
#pragma unroll
  for (int f = 0; f < 5; ++f){
    int off = f*20;
    float run = 0.f;
    for (int k = 0; k < 20; ++k){
      run += src[off + k];
      Pn[(size_t)(off + k)*512 + d] = run;
    }
  }
}

// ---------------- K1: MFMA prep — swvs GEMM + LN + counts + OH --------------
__global__ __launch_bounds__(256) void k_prep_mfma(
    const float* __restrict__ vf, const float* __restrict__ mask,
    const float* __restrict__ eoh, const float* __restrict__ subs,
    const float* __restrict__ ln_g, const float* __restrict__ ln_b,
    _Float16* __restrict__ Abuf, int* __restrict__ cpk){
  __shared__ _Float16 s_mvfT[G_*A_];   // [g][a], masked vf, 32 KB
  __shared__ _Float16 s_sm[128*A_];    // [s][a], raw subs, 8 KB
  __shared__ float s_m[A_];
  __shared__ float s_e[A_*5];
  __shared__ float s_ssum[128];
  __shared__ float s_red1[4][16];
  __shared__ float s_red2[4][16];
  int tid = threadIdx.x;
  int bx = blockIdx.x, b = blockIdx.y;
  int lane = tid & 63, w = tid >> 6;
  int q = lane >> 4, l15 = lane & 15;
  size_t row0 = (size_t)b*S_ + (size_t)bx*128;
  if (tid < A_)   s_m[tid] = mask[b*A_ + tid];
  if (tid < A_*5) s_e[tid] = eoh[b*A_*5 + tid];
  __syncthreads();
  {
    int p = tid & 15, gseg = tid >> 4;
    float mk0 = s_m[2*p], mk1 = s_m[2*p+1];
    const float* v0 = vf + ((size_t)b*A_ + 2*p)*G_ + gseg*32;
    const float* v1 = v0 + G_;
#pragma unroll
    for (int i = 0; i < 32; ++i){
      int g = gseg*32 + i;
      half2v h; h[0] = (_Float16)(v0[i]*mk0); h[1] = (_Float16)(v1[i]*mk1);
      *(half2v*)(s_mvfT + g*A_ + 2*p) = h;
    }
  }
  {
    int s = tid >> 1, hh = tid & 1;
    const float* sp = subs + (row0 + s)*A_ + hh*16;
#pragma unroll
    for (int i = 0; i < 16; i += 2){
      half2v h; h[0] = (_Float16)sp[i]; h[1] = (_Float16)sp[i+1];
      *(half2v*)(s_sm + s*A_ + hh*16 + i) = h;
    }
  }
  __syncthreads();
  if (tid < 128){
    int s = tid;
    float ssum = 0.f, c0=0.f, c1=0.f, c2=0.f, c3=0.f, c4=0.f;
#pragma unroll
    for (int a = 0; a < A_; ++a){
      float v = (float)s_sm[s*A_ + a];
      ssum += v * s_m[a];
      c0 += v * s_e[a*5+0]; c1 += v * s_e[a*5+1]; c2 += v * s_e[a*5+2];
      c3 += v * s_e[a*5+3]; c4 += v * s_e[a*5+4];
    }
    int cc[5];
    cc[0] = min(max((int)(c0+0.5f),0),19); cc[1] = min(max((int)(c1+0.5f),0),19);
    cc[2] = min(max((int)(c2+0.5f),0),19); cc[3] = min(max((int)(c3+0.5f),0),19);
    cc[4] = min(max((int)(c4+0.5f),0),19);
    cpk[row0 + s] = cc[0] | (cc[1]<<6) | (cc[2]<<12) | (cc[3]<<18) | (cc[4]<<24);
    s_ssum[s] = ssum;
    _Float16* dst = Abuf + (row0 + s)*KC_ + 512;
#pragma unroll
    for (int t = 0; t < 16; ++t){
      half8 hv;
#pragma unroll
      for (int u = 0; u < 8; ++u){
        int k = t*8 + u;
        float v = 0.f;
        if (k < 100){ int f = k/20, l = k - f*20; v = (l <= cc[f]) ? 1.f : 0.f; }
        hv[u] = (_Float16)v;
      }
      *(half8*)(dst + t*8) = hv;
    }
  }
  half8 bf[8]; float lng[8], lnb[8];
#pragma unroll
  for (int t = 0; t < 8; ++t){
    int g = w*128 + t*16 + l15;
    bf[t] = *(const half8*)(s_mvfT + g*A_ + q*8);
    lng[t] = ln_g[g]; lnb[t] = ln_b[g];
  }
  __syncthreads();
  for (int gi = 0; gi < 8; ++gi){
    half8 af = *(const half8*)(s_sm + (gi*16 + l15)*A_ + q*8);
    floatx4 c[8];
#pragma unroll
    for (int t = 0; t < 8; ++t){
      floatx4 z = {0.f, 0.f, 0.f, 0.f};
      c[t] = __builtin_amdgcn_mfma_f32_16x16x32_f16(af, bf[t], z, 0, 0, 0);
    }
    float p1[4] = {0.f,0.f,0.f,0.f}, p2[4] = {0.f,0.f,0.f,0.f};
#pragma unroll
    for (int t = 0; t < 8; ++t)
#pragma unroll
      for (int r = 0; r < 4; ++r){ float v = c[t][r]; p1[r] += v; p2[r] += v*v; }
#pragma unroll
    for (int off = 1; off < 16; off <<= 1)
#pragma unroll
      for (int r = 0; r < 4; ++r){
        p1[r] += __shfl_xor(p1[r], off);
        p2[r] += __shfl_xor(p2[r], off);
      }
    if (l15 == 0){
#pragma unroll
      for (int r = 0; r < 4; ++r){ s_red1[w][q*4+r] = p1[r]; s_red2[w][q*4+r] = p2[r]; }
    }
    __syncthreads();
#pragma unroll
    for (int r = 0; r < 4; ++r){
      int sl = gi*16 + q*4 + r;
      int rr = q*4 + r;
      float t1 = s_red1[0][rr] + s_red1[1][rr] + s_red1[2][rr] + s_red1[3][rr];
      float t2 = s_red2[0][rr] + s_red2[1][rr] + s_red2[2][rr] + s_red2[3][rr];
      float inv = 1.f/(s_ssum[sl] + 1e-4f);
      float mu = t1*inv*(1.f/512.f);
      float var = t2*inv*inv*(1.f/512.f) - mu*mu;
      float rs = rsqrtf(var + 1e-5f);
      _Float16* orow = Abuf + (row0 + sl)*KC_;
#pragma unroll
      for (int t = 0; t < 8; ++t){
        float o = (c[t][r]*inv - mu)*rs*lng[t] + lnb[t];
        orow[w*128 + t*16 + l15] = (_Float16)o;
      }
    }
    __syncthreads();
  }
}

// ---------------- K2: fused gh GEMM (3 gates) + GRU elementwise -------------
// grid (8, 512), 512 threads. XCD swizzle: xcd = blockIdx.x (linear%8);
// XCD k owns m-tiles [k*64, k*64+64), d-tile fastest -> A-tile stays in one
// XCD's L2 across its 8 d-blocks. Block tile: 128m x 192n (3 gates x 64 d).
// Waves 2x4: wave tile 64m x 48n -> acc 12 floatx4 = 48 regs, 12 MFMA / 7 reads.
__global__ __launch_bounds__(512) void k_gru_fused(
    const _Float16* __restrict__ Abuf, const _Float16* __restrict__ Wcat,
    const float* __restrict__ Pn, const float* __restrict__ bih,
    const float* __restrict__ bhh, const int* __restrict__ cpk,
    _Float16* __restrict__ H){
  __shared__ _Float16 smA[128*32];   // 8 KB
  __shared__ _Float16 smB[192*32];   // 12 KB
  int tid = threadIdx.x;
  int lane = tid & 63, wvid = tid >> 6;      // 8 waves
  int wm = wvid & 1, wn = wvid >> 1;         // wm in {0,1}, wn in {0..3}
  int q = lane >> 4, l15 = lane & 15;
  int mt = blockIdx.x*64 + (blockIdx.y >> 3);
  int dt = blockIdx.y & 7;
  int m0 = mt*128, n0 = dt*64;
  floatx4 acc[3][4] = {};
  int offA[4], offB[3];
#pragma unroll
  for (int i = 0; i < 4; ++i){
    int r = wm*64 + i*16 + l15;
    offA[i] = (r*4 + (q ^ ((r>>2)&3)))*8;
  }
#pragma unroll
  for (int g = 0; g < 3; ++g){
    int rb = g*64 + wn*16 + l15;
    offB[g] = (rb*4 + (q ^ ((rb>>2)&3)))*8;
  }
  // staging: A 512 units (8 segs, 1/wave); B 768 units (12 segs: wave w does
  // seg w, waves 0-3 also seg 8+w)
  const _Float16* gA;
  {
    int u = wvid*64 + lane;
    int r = u >> 2, c = (u & 3) ^ ((r >> 2) & 3);
    gA = Abuf + (size_t)(m0 + r)*KC_ + c*8;
  }
  const _Float16* gB0;
  {
    int u = wvid*64 + lane;
    int rb = u >> 2, c = (u & 3) ^ ((rb >> 2) & 3);
    int grow = (rb >> 6)*512 + n0 + (rb & 63);
    gB0 = Wcat + (size_t)grow*KC_ + c*8;
  }
  const _Float16* gB1 = nullptr;
  if (wvid < 4){
    int u = (8 + wvid)*64 + lane;
    int rb = u >> 2, c = (u & 3) ^ ((rb >> 2) & 3);
    int grow = (rb >> 6)*512 + n0 + (rb & 63);
    gB1 = Wcat + (size_t)grow*KC_ + c*8;
  }
  for (int kc = 0; kc < KC_; kc += 32){
    __builtin_amdgcn_global_load_lds((gas_t)(gA + kc), (las_t)(smA + wvid*512), 16, 0, 0);
    __builtin_amdgcn_global_load_lds((gas_t)(gB0 + kc), (las_t)(smB + wvid*512), 16, 0, 0);
    if (wvid < 4)
      __builtin_amdgcn_global_load_lds((gas_t)(gB1 + kc), (las_t)(smB + (8+wvid)*512), 16, 0, 0);
    __syncthreads();
    half8 af[4], bfv[3];
#pragma unroll
    for (int i = 0; i < 4; ++i) af[i] = *(const half8*)(smA + offA[i]);
#pragma unroll
    for (int g = 0; g < 3; ++g) bfv[g] = *(const half8*)(smB + offB[g]);
#pragma unroll
    for (int g = 0; g < 3; ++g)
#pragma unroll
      for (int i = 0; i < 4; ++i)
        acc[g][i] = __builtin_amdgcn_mfma_f32_16x16x32_f16(af[i], bfv[g], acc[g][i], 0, 0, 0);
    __syncthreads();
  }
  // epilogue: one d per lane
  int d = n0 + wn*16 + l15;
  float br  = bih[d] + bhh[d];
  float bz  = bih[512+d] + bhh[512+d];
  float bnh = bhh[1024+d];
  float bni = bih[1024+d];
#pragma unroll
  for (int i = 0; i < 4; ++i){
#pragma unroll
    for (int r = 0; r < 4; ++r){
      int m = m0 + wm*64 + i*16 + q*4 + r;
      int cp = cpk[m];
      int k0 =  (cp      ) & 63;
      int k1 = ((cp >> 6 ) & 63) + 20;
      int k2 = ((cp >> 12) & 63) + 40;
      int k3 = ((cp >> 18) & 63) + 60;
      int k4 = ((cp >> 24) & 63) + 80;
      float in_ = bni + Pn[(size_t)k0*512 + d] + Pn[(size_t)k1*512 + d]
                + Pn[(size_t)k2*512 + d] + Pn[(size_t)k3*512 + d]
                + Pn[(size_t)k4*512 + d];
      float gr = acc[0][i][r] + br;
      float gz = acc[1][i][r] + bz;
      float hn = acc[2][i][r] + bnh;
      float rrv = sigmoidf_(gr);
      float zz  = sigmoidf_(gz);
      float nn  = tanhf_(in_ + rrv*hn);
      float hp = (float)Abuf[(size_t)m*KC_ + d];
      H[(size_t)m*G_ + d] = (_Float16)((1.f-zz)*nn + zz*hp);
    }
  }
}

// ---------------- K3: FF fp16 MFMA GEMM  Out = relu(A @ W^T + bias) ---------
// K=512, N=512 fixed. grid (8, 256): xcd = blockIdx.x; XCD k owns m-tiles
// [k*64, k*64+64), n fastest.
__global__ __launch_bounds__(256) void k_gemm(
    const _Float16* __restrict__ A, const _Float16* __restrict__ W,
    const float* __restrict__ bias, _Float16* __restrict__ Out){
  __shared__ _Float16 smA[128*32];
  __shared__ _Float16 smB[128*32];
  int tid = threadIdx.x;
  int lane = tid & 63, wvid = tid >> 6;
  int wm = wvid & 1, wn = wvid >> 1;
  int q = lane >> 4, l15 = lane & 15;
  int mt = blockIdx.x*64 + (blockIdx.y >> 2);
  int nt = blockIdx.y & 3;
  int m0 = mt*128, n0 = nt*128;
  floatx4 acc[4][4] = {};
  int offA[4], offB[4];
#pragma unroll
  for (int i = 0; i < 4; ++i){
    int r = wm*64 + i*16 + l15;
    offA[i] = (r*4 + (q ^ ((r>>2)&3)))*8;
    int rb = wn*64 + i*16 + l15;
    offB[i] = (rb*4 + (q ^ ((rb>>2)&3)))*8;
  }
  int uA[2];
  const _Float16 *gA[2], *gB[2];
#pragma unroll
  for (int t = 0; t < 2; ++t){
    int seg = wvid*2 + t;
    int u = seg*64 + lane;
    int r = u >> 2, c = (u & 3) ^ ((r >> 2) & 3);
    uA[t] = seg;
    gA[t] = A + (size_t)(m0 + r)*G_ + c*8;
    gB[t] = W + (size_t)(n0 + r)*G_ + c*8;
  }
  for (int kc = 0; kc < G_; kc += 32){
#pragma unroll
    for (int t = 0; t < 2; ++t){
      __builtin_amdgcn_global_load_lds((gas_t)(gA[t] + kc), (las_t)(smA + uA[t]*512), 16, 0, 0);
      __builtin_amdgcn_global_load_lds((gas_t)(gB[t] + kc), (las_t)(smB + uA[t]*512), 16, 0, 0);
    }
    __syncthreads();
    half8 af[4], bfv[4];
#pragma unroll
    for (int i = 0; i < 4; ++i) af[i] = *(const half8*)(smA + offA[i]);
#pragma unroll
    for (int j = 0; j < 4; ++j) bfv[j] = *(const half8*)(smB + offB[j]);
#pragma unroll
    for (int i = 0; i < 4; ++i)
#pragma unroll
      for (int j = 0; j < 4; ++j)
        acc[i][j] = __builtin_amdgcn_mfma_f32_16x16x32_f16(af[i], bfv[j], acc[i][j], 0, 0, 0);
    __syncthreads();
  }
#pragma unroll
  for (int j = 0; j < 4; ++j){
    int n = n0 + wn*64 + j*16 + l15;
    float bv = bias[n];
#pragma unroll
    for (int i = 0; i < 4; ++i){
#pragma unroll
      for (int r = 0; r < 4; ++r){
        int m = m0 + wm*64 + i*16 + q*4 + r;
        Out[(size_t)m*G_ + n] = (_Float16)fmaxf(acc[i][j][r] + bv, 0.f);
      }
    }
  }
}

// ---------------- K4: final LN + score (fp16 in, fp32 out) ------------------
__global__ __launch_bounds__(256) void k_ln_score(
    const _Float16* __restrict__ X, const float* __restrict__ g,
    const float* __restrict__ bta, const float* __restrict__ Ws,
    const float* __restrict__ bs, float* __restrict__ scores){
  int tid = threadIdx.x, lane = tid & 63, wv = tid >> 6;
  size_t row0 = (size_t)blockIdx.x*32 + wv*8;
  int e0 = lane*8;
  float wv_[8], gv[8], bv[8];
  *(float4*)(wv_ ) = *(const float4*)(Ws + e0);
  *(float4*)(wv_+4) = *(const float4*)(Ws + e0 + 4);
  *(float4*)(gv  ) = *(const float4*)(g + e0);
  *(float4*)(gv+4) = *(const float4*)(g + e0 + 4);
  *(float4*)(bv  ) = *(const float4*)(bta + e0);
  *(float4*)(bv+4) = *(const float4*)(bta + e0 + 4);
  float bsv = bs[0];
  for (int rr = 0; rr < 8; ++rr){
    size_t row = row0 + rr;
    half8 hx = *(const half8*)(X + row*G_ + e0);
    float xv[8];
#pragma unroll
    for (int t = 0; t < 8; ++t) xv[t] = (float)hx[t];
    float s1 = 0.f, s2 = 0.f;
#pragma unroll
    for (int t = 0; t < 8; ++t){ s1 += xv[t]; s2 += xv[t]*xv[t]; }
    s1 = wave_sum_f(s1); s2 = wave_sum_f(s2);
    float mu = s1*(1.f/512.f);
    float var = s2*(1.f/512.f) - mu*mu;
    float rs = rsqrtf(var + 1e-5f);
    float sc = 0.f;
#pragma unroll
    for (int t = 0; t < 8; ++t) sc += ((xv[t]-mu)*rs*gv[t] + bv[t])*wv_[t];
    sc = wave_sum_f(sc);
    if (lane == 0) scores[row] = sc + bsv;
  }
}

// ---------------- K5: softmax over S per batch ------------------------------
__global__ __launch_bounds__(256) void k_softmax(
    const float* __restrict__ scores, float* __restrict__ probs){
  __shared__ float red[4];
  int b = blockIdx.x, tid = threadIdx.x, lane = tid & 63, wv = tid >> 6;
  const float* sp = scores + (size_t)b*S_;
  float mx = -1e30f;
  for (int i = tid; i < S_; i += 256) mx = fmaxf(mx, sp[i]);
  mx = wave_max_f(mx);
  if (lane == 0) red[wv] = mx;
  __syncthreads();
  mx = fmaxf(fmaxf(red[0], red[1]), fmaxf(red[2], red[3]));
  __syncthreads();
  float sum = 0.f;
  for (int i = tid; i < S_; i += 256) sum += __expf(sp[i]-mx);
  sum = wave_sum_f(sum);
  if (lane == 0) red[wv] = sum;
  __syncthreads();
  sum = red[0]+red[1]+red[2]+red[3];
  float inv = 1.f/sum;
  for (int i = tid; i < S_; i += 256)
    probs[(size_t)b*S_ + i] = __expf(sp[i]-mx)*inv;
}

// ---------------- K6: spectrum scatter --------------------------------------
__global__ __launch_bounds__(256) void k_spect(
    const float* __restrict__ peaks, const float* __restrict__ probs,
    float* __restrict__ spect){
  __shared__ float bins[512];
  int b = blockIdx.x, tid = threadIdx.x;
  bins[tid] = 0.f; bins[tid+256] = 0.f;
  __syncthreads();
  for (int i = tid; i < S_*M_; i += 256){
    int s = i >> 3, m = i & 7;
    const float* pk = peaks + (((size_t)b*S_ + s)*M_ + m)*2;
    float mass = pk[0], inten = pk[1];
    float p = probs[(size_t)b*S_ + s];
    int bin = (int)rintf(mass);
    bin = min(max(bin, 0), 511);
    atomicAdd(&bins[bin], inten*p);
  }
  __syncthreads();
  spect[(size_t)b*512 + tid]       = bins[tid];
  spect[(size_t)b*512 + tid + 256] = bins[tid+256];
}

// ---------------- launcher --------------------------------------------------
extern "C" void kernel_launch(void* const* d_in, const int* in_sizes, int n_in,
                              void* d_out, int out_size, void* d_ws, size_t ws_size,
                              hipStream_t stream) {
  const float* vf       = (const float*)d_in[0];
  const float* mask     = (const float*)d_in[1];
  const float* eoh      = (const float*)d_in[2];
  const float* subs     = (const float*)d_in[4];
  const float* peaks    = (const float*)d_in[5];
  const float* ln_sub_g = (const float*)d_in[6];
  const float* ln_sub_b = (const float*)d_in[7];
  const float* W_ih     = (const float*)d_in[8];
  const float* W_hh     = (const float*)d_in[9];
  const float* b_ih     = (const float*)d_in[10];
  const float* b_hh     = (const float*)d_in[11];
  const float* W1       = (const float*)d_in[12];
  const float* b1       = (const float*)d_in[13];
  const float* W2a      = (const float*)d_in[14];
  const float* b2a      = (const float*)d_in[15];
  const float* W2b      = (const float*)d_in[16];
  const float* b2b      = (const float*)d_in[17];
  const float* ln_pre_g = (const float*)d_in[18];
  const float* ln_pre_b = (const float*)d_in[19];
  const float* Ws       = (const float*)d_in[20];
  const float* bs       = (const float*)d_in[21];
  float* out = (float*)d_out;            // [0,8192) spect, [8192,73728) probs
  float* probs_out = out + (size_t)B_*512;

  // workspace carve — total ~155 MB (ws >= ~206 MB proven in round 3)
  char* w = (char*)d_ws;
  float* Pn = (float*)w;         w += (size_t)100*512*4;
  int*   cpk = (int*)w;          w += (size_t)BS_*4;
  float* scores = (float*)w;     w += (size_t)BS_*4;
  _Float16* Wcat = (_Float16*)w; w += (size_t)NG_*KC_*2;
  _Float16* W1h  = (_Float16*)w; w += (size_t)G_*G_*2;
  _Float16* W2ah = (_Float16*)w; w += (size_t)G_*G_*2;
  _Float16* W2bh = (_Float16*)w; w += (size_t)G_*G_*2;
  _Float16* Abuf = (_Float16*)w; w += (size_t)BS_*KC_*2;       // 84 MB
  _Float16* bufh0 = (_Float16*)w;                              // 67 MB (H)
  _Float16* bufh1 = Abuf;        // FF ping-pong reuses A region (84 >= 67 MB)

  k_cvt<<<(G_*G_/4+255)/256, 256, 0, stream>>>(W1,  W1h,  G_*G_);
  k_cvt<<<(G_*G_/4+255)/256, 256, 0, stream>>>(W2a, W2ah, G_*G_);
  k_cvt<<<(G_*G_/4+255)/256, 256, 0, stream>>>(W2b, W2bh, G_*G_);
  k_buildw<<<NG_, 64, 0, stream>>>(W_hh, W_ih, Wcat);
  k_pn<<<2, 256, 0, stream>>>(W_ih, Pn);
  k_prep_mfma<<<dim3(S_/128, B_), 256, 0, stream>>>(vf, mask, eoh, subs,
                                                    ln_sub_g, ln_sub_b, Abuf, cpk);
  k_gru_fused<<<dim3(8, 512), 512, 0, stream>>>(Abuf, Wcat, Pn, b_ih, b_hh,
                                                cpk, bufh0);
  k_gemm<<<dim3(8, 256), 256, 0, stream>>>(bufh0, W1h,  b1,  bufh1);
  k_gemm<<<dim3(8, 256), 256, 0, stream>>>(bufh1, W2ah, b2a, bufh0);
  k_gemm<<<dim3(8, 256), 256, 0, stream>>>(bufh0, W2bh, b2b, bufh1);
  k_ln_score<<<BS_/32, 256, 0, stream>>>(bufh1, ln_pre_g, ln_pre_b, Ws, bs, scores);
  k_softmax<<<B_, 256, 0, stream>>>(scores, probs_out);
  k_spect<<<B_, 256, 0, stream>>>(peaks, probs_out, out);
}